// Round 12
// baseline (772.183 us; speedup 1.0000x reference)
//
#include <hip/hip_runtime.h>

// Problem constants
#define Sdim   2048
#define Hdim   4096
#define NHEADS 32
#define Dh     128
#define Mrows  4096      // B*S
#define QKVLD  12288     // 3*H

typedef __attribute__((ext_vector_type(8))) short short8;
typedef __attribute__((ext_vector_type(4))) float f32x4;
typedef __attribute__((ext_vector_type(4))) float float4v;

__device__ __forceinline__ short f2bf(float f) {
  union { float f; unsigned u; } x; x.f = f;
  unsigned r = x.u + 0x7fffu + ((x.u >> 16) & 1u);  // RNE
  return (short)(r >> 16);
}
__device__ __forceinline__ float bf2f(short s) {
  union { unsigned u; float f; } x; x.u = ((unsigned)(unsigned short)s) << 16;
  return x.f;
}

__device__ __forceinline__ void gload_lds16(const void* g, void* l) {
  __builtin_amdgcn_global_load_lds(
      (const __attribute__((address_space(1))) void*)g,
      (__attribute__((address_space(3))) void*)l, 16, 0, 0);
}

// ---------------- fp32 -> bf16 convert (8 elems/thread) ----------------
__global__ void k_cvt(const float* __restrict__ src, short* __restrict__ dst, int n8) {
  int idx = blockIdx.x * blockDim.x + threadIdx.x;
  if (idx >= n8) return;
  const float4v* s = (const float4v*)src + (size_t)idx * 2;
  float4v a = s[0], b = s[1];
  short8 o;
  o[0] = f2bf(a.x); o[1] = f2bf(a.y); o[2] = f2bf(a.z); o[3] = f2bf(a.w);
  o[4] = f2bf(b.x); o[5] = f2bf(b.y); o[6] = f2bf(b.z); o[7] = f2bf(b.w);
  *((short8*)dst + idx) = o;
}

// ---- transpose + convert, vectorized both sides: dst[C][R] bf16 = src[R][C] f32 ----
__global__ void k_tcvt64(const float* __restrict__ src, short* __restrict__ dst,
                         int R, int C) {
  __shared__ float t[64][65];
  const int tid = threadIdx.x;          // 256
  const int r0 = blockIdx.y * 64, c0 = blockIdx.x * 64;
  const int ir = tid >> 4, ic = (tid & 15) << 2;
#pragma unroll
  for (int p = 0; p < 4; ++p) {
    const float4v v = *(const float4v*)(src + (size_t)(r0 + p * 16 + ir) * C + c0 + ic);
    t[p * 16 + ir][ic] = v.x; t[p * 16 + ir][ic + 1] = v.y;
    t[p * 16 + ir][ic + 2] = v.z; t[p * 16 + ir][ic + 3] = v.w;
  }
  __syncthreads();
  const int oc = tid >> 3, orr = (tid & 7) << 3;
#pragma unroll
  for (int p = 0; p < 2; ++p) {
    int c = p * 32 + oc;
    short8 o;
#pragma unroll
    for (int j = 0; j < 8; ++j) o[j] = f2bf(t[orr + j][c]);
    *(short8*)(dst + (size_t)(c0 + c) * R + r0 + orr) = o;
  }
}

// ------- V transpose, vectorized: Vt[(b*32+h)*128+d][s] = qkv[b*2048+s][8192+hc] -------
__global__ void k_vt64(const short* __restrict__ qkv, short* __restrict__ vt) {
  __shared__ short tile[4096];  // [64 s][64 d] swizzled
  const int tid = threadIdx.x;          // 256
  const int c0 = blockIdx.x * 64;       // d-col base (0..4095)
  const int s0 = blockIdx.y * 64;       // token base within batch
  const int b  = blockIdx.z;
#pragma unroll
  for (int j = 0; j < 2; ++j) {
    int chunk = j * 256 + tid;
    int row = chunk >> 3, c8 = chunk & 7;
    short8 v = *(const short8*)(qkv + (size_t)(b * 2048 + s0 + row) * QKVLD + 8192 + c0 + c8 * 8);
    int sw = c8 ^ ((row ^ (row >> 3)) & 7);
    *(short8*)((char*)tile + row * 128 + sw * 16) = v;
  }
  __syncthreads();
#pragma unroll
  for (int j = 0; j < 2; ++j) {
    int chunk = j * 256 + tid;
    int d = chunk >> 3, s8 = (chunk & 7) << 3;
    short8 o;
#pragma unroll
    for (int j2 = 0; j2 < 8; ++j2) {
      int s = s8 + j2;
      int sw = ((d >> 3) ^ ((s ^ (s >> 3)) & 7));
      o[j2] = *(const short*)((const char*)tile + s * 128 + sw * 16 + (d & 7) * 2);
    }
    *(short8*)(vt + (size_t)(b * 4096 + c0 + d) * Sdim + s0 + s8) = o;
  }
}

// ============ 256x256-tile bf16 GEMM, 8 waves, 4 phases/K-tile, counted vmcnt ============
__device__ __forceinline__ void stage_half256(const short* G, int ld, int row0, int kcol,
                                              char* lds, int tid) {
#pragma unroll
  for (int j = 0; j < 2; ++j) {
    int p = j * 512 + tid;            // 16B chunk id in [0,1024): 8 chunks per 64-col row
    int r = p >> 3;
    int c = ((p & 7) ^ (r & 7)) << 3; // swizzled source column (elements)
    gload_lds16(G + (size_t)(row0 + r) * ld + kcol + c,
                lds + ((j * 512 + (tid & 448)) << 4));
  }
}

#define MFMA_Q(qm, qn)                                                                   \
  do {                                                                                   \
    __builtin_amdgcn_s_setprio(1);                                                       \
    _Pragma("unroll")                                                                    \
    for (int m4 = 0; m4 < 4; ++m4)                                                       \
      _Pragma("unroll")                                                                  \
      for (int n2 = 0; n2 < 2; ++n2) {                                                   \
        acc[(qm)*4+m4][(qn)*2+n2] = __builtin_amdgcn_mfma_f32_16x16x32_bf16(             \
            av[m4][0], bv[(qn)*2+n2][0], acc[(qm)*4+m4][(qn)*2+n2], 0, 0, 0);            \
        acc[(qm)*4+m4][(qn)*2+n2] = __builtin_amdgcn_mfma_f32_16x16x32_bf16(             \
            av[m4][1], bv[(qn)*2+n2][1], acc[(qm)*4+m4][(qn)*2+n2], 0, 0, 0);            \
      }                                                                                  \
    __builtin_amdgcn_s_setprio(0);                                                       \
  } while (0)

#define PH_BARRIER()                    \
  do {                                  \
    __builtin_amdgcn_s_barrier();       \
    __builtin_amdgcn_sched_barrier(0);  \
  } while (0)

template<bool C_F32>
__global__ __launch_bounds__(512, 2) void k_gemm256(const short* __restrict__ A, int lda,
                                                    const short* __restrict__ Bt, int ldb,
                                                    void* __restrict__ Cp, int ldc,
                                                    int Ndim, int Kdim) {
  __shared__ __align__(16) char smem[131072];
  const int tid  = threadIdx.x;
  const int lane = tid & 63;
  const int wave = tid >> 6;
  const int lo = lane & 15, hi = lane >> 4;
  const int wr = wave >> 2, wc = wave & 3;   // 2M x 4N waves; per-wave out 128x64

  // T1: XCD-aware bijective block swizzle (grid % 8 == 0 for all our calls)
  const int nblk = gridDim.x;
  const int lid = (blockIdx.x & 7) * (nblk >> 3) + (blockIdx.x >> 3);
  const int nbn = Ndim >> 8;
  const int bm0 = (lid / nbn) << 8;
  const int bn0 = (lid % nbn) << 8;

  f32x4 acc[8][4];
#pragma unroll
  for (int i = 0; i < 8; ++i)
#pragma unroll
    for (int j = 0; j < 4; ++j) acc[i][j] = (f32x4){0.f, 0.f, 0.f, 0.f};

  short8 av[4][2], bv[4][2];
  const int swz = (lo & 7) << 4;
  const int brow = (wc & 1) * 64;

  // prologue: K-tile 0 -> slot 0
  stage_half256(Bt, ldb, bn0,       0, smem + 32768,         tid);
  stage_half256(Bt, ldb, bn0 + 128, 0, smem + 32768 + 16384, tid);
  stage_half256(A,  lda, bm0,       0, smem,                 tid);
  stage_half256(A,  lda, bm0 + 128, 0, smem + 16384,         tid);

  const int NK = Kdim >> 6;
  for (int kt = 0; kt < NK; ++kt) {
    const int cur = kt & 1;
    const char* Ab = smem + cur * 65536 + wr * 16384;                 // wave's A half
    const char* Bb = smem + cur * 65536 + 32768 + (wc >> 1) * 16384;  // wave's B half
    char* nA = smem + (cur ^ 1) * 65536;
    char* nB = nA + 32768;
    const int kc = (kt + 1) << 6;
    const bool pf = (kt + 1 < NK);

    // ---- phase 0: stage B'h0+B'h1; counted drain; read A[0-3],B[0-1]; MFMA (0,0) ----
    if (pf) {
      stage_half256(Bt, ldb, bn0,       kc, nB,         tid);
      stage_half256(Bt, ldb, bn0 + 128, kc, nB + 16384, tid);
      asm volatile("s_waitcnt vmcnt(4)" ::: "memory");   // prev 8 landed; own 4 in flight
    } else {
      asm volatile("s_waitcnt vmcnt(0)" ::: "memory");   // final tile: full drain
    }
    PH_BARRIER();   // after this, slot cur is fully landed for ALL waves
#pragma unroll
    for (int m4 = 0; m4 < 4; ++m4)
#pragma unroll
      for (int ks = 0; ks < 2; ++ks)
        av[m4][ks] = *(const short8*)(Ab + (m4 * 16 + lo) * 128 + ((ks * 64 + hi * 16) ^ swz));
#pragma unroll
    for (int ni = 0; ni < 2; ++ni)
#pragma unroll
      for (int ks = 0; ks < 2; ++ks)
        bv[ni][ks] = *(const short8*)(Bb + (brow + ni * 16 + lo) * 128 + ((ks * 64 + hi * 16) ^ swz));
    MFMA_Q(0, 0);
    // hoisted reads for phase 1 (slot cur is landed)
#pragma unroll
    for (int ni = 2; ni < 4; ++ni)
#pragma unroll
      for (int ks = 0; ks < 2; ++ks)
        bv[ni][ks] = *(const short8*)(Bb + (brow + ni * 16 + lo) * 128 + ((ks * 64 + hi * 16) ^ swz));

    // ---- phase 1: stage A'h0+A'h1; MFMA (0,1); hoist A-rows 64-127 reads ----
    if (pf) {
      stage_half256(A, lda, bm0,       kc, nA,         tid);
      stage_half256(A, lda, bm0 + 128, kc, nA + 16384, tid);
    }
    PH_BARRIER();
    MFMA_Q(0, 1);
#pragma unroll
    for (int m4 = 0; m4 < 4; ++m4)
#pragma unroll
      for (int ks = 0; ks < 2; ++ks)
        av[m4][ks] = *(const short8*)(Ab + ((64 + m4 * 16 + lo) * 128) + ((ks * 64 + hi * 16) ^ swz));

    // ---- phase 2: MFMA (1,0) ----
    PH_BARRIER();
    MFMA_Q(1, 0);

    // ---- phase 3: MFMA (1,1) ----
    PH_BARRIER();
    MFMA_Q(1, 1);
  }

  // epilogue: C/D layout row=(lane>>4)*4+reg, col=lane&15
#pragma unroll
  for (int mi = 0; mi < 8; ++mi)
#pragma unroll
    for (int r = 0; r < 4; ++r) {
      int row = bm0 + wr * 128 + mi * 16 + hi * 4 + r;
#pragma unroll
      for (int ni = 0; ni < 4; ++ni) {
        int col = bn0 + wc * 64 + ni * 16 + lo;
        if (C_F32) ((float*)Cp)[(size_t)row * ldc + col] = acc[mi][ni][r];
        else       ((short*)Cp)[(size_t)row * ldc + col] = f2bf(acc[mi][ni][r]);
      }
    }
}

// ------------- RoPE on K only, vectorized (Q-RoPE is fused into k_attn) -------------
__global__ void k_ropeK(short* qkv, const int* __restrict__ positions) {
  int idx = blockIdx.x * 256 + threadIdx.x;   // (row, h, t): 4096*32*8 threads
  int t = idx & 7;
  int h = (idx >> 3) & 31;
  int row = idx >> 8;
  float pos = (float)positions[row];
  size_t o = (size_t)row * QKVLD + 4096 + h * 128 + t * 8;
  short8 k1 = *(short8*)(qkv + o), k2 = *(short8*)(qkv + o + 64);
#pragma unroll
  for (int j = 0; j < 8; ++j) {
    int d = t * 8 + j;
    float inv = exp2f((float)d * -0.2076205059304570f);
    float ang = pos * inv, s, c;
    sincosf(ang, &s, &c);
    float b1 = bf2f(k1[j]), b2 = bf2f(k2[j]);
    k1[j] = f2bf(b1 * c - b2 * s); k2[j] = f2bf(b2 * c + b1 * s);
  }
  *(short8*)(qkv + o) = k1; *(short8*)(qkv + o + 64) = k2;
}

// ---------------- causal flash attention (dbuf K/Vt, ones-column + defer-max) ----------------
// R12: Q-RoPE + softmax scale (SEXP) folded into the Q register load — the Q-frag lane
// holds both d (ks) and d+64 (ks+2) at the same j, so the rotation is lane-local.
// The per-kv-tile "*SEXP" multiply is deleted from the softmax loop.
__device__ __forceinline__ void stage_kv(const short* Kb, const short* Vtb, int kv0,
                                         char* kbuf, char* vbuf, int tid, int wave) {
#pragma unroll
  for (int i = 0; i < 4; ++i) {
    int p = i * 256 + tid;            // 16B chunk id in [0,1024)
    int r = p >> 4;                   // kv row (16 chunks/row)
    int c = (p & 15) ^ (r & 7);       // swizzled chunk within row
    gload_lds16(Kb + (size_t)(kv0 + r) * QKVLD + (c << 3),
                kbuf + ((i * 256 + wave * 64) << 4));
  }
#pragma unroll
  for (int i = 0; i < 4; ++i) {
    int p = i * 256 + tid;
    int r = p >> 3;                   // d row (8 chunks/row)
    int c = (p & 7) ^ (r & 7);        // swizzled chunk within row
    gload_lds16(Vtb + (size_t)r * Sdim + kv0 + (c << 3),
                vbuf + ((i * 256 + wave * 64) << 4));
  }
}

__global__ __launch_bounds__(256, 2) void k_attn(short* __restrict__ qkv,
                                                 const short* __restrict__ Vt,
                                                 const int* __restrict__ positions) {
  __shared__ __align__(16) char smem[81920];
  const int tid  = threadIdx.x;
  const int lane = tid & 63;
  const int wave = tid >> 6;
  const int lo = lane & 15, hi = lane >> 4;

  const int bid = blockIdx.x;
  const int lid = (bid & 7) * 128 + (bid >> 3);
  const int bh = lid >> 4;
  const int qt = 15 - (lid & 15);     // heavy tiles first
  const int b = bh >> 5, h = bh & 31;
  const int q0 = qt << 7;

  short* base = qkv + (size_t)b * Sdim * QKVLD;
  const short* Qb = base + h * Dh;
  const short* Kb = base + Hdim + h * Dh;
  const short* Vtb = Vt + (size_t)(b * 32 + h) * 128 * Sdim;
  const int qrow0 = q0 + wave * 32;

  short* Pw = (short*)(smem + 65536 + wave * 4096);

  const float SEXP = 0.088388347648318447f * 1.4426950408889634f;  // scale*log2e

  // Q into registers (A-frag layout: row=lo, k=ks*32+hi*8), then in-register
  // RoPE rotate (pairs (ks, ks+2) at same j) + SEXP pre-scale.
  short8 qf[2][4];
#pragma unroll
  for (int mi = 0; mi < 2; ++mi)
#pragma unroll
    for (int ks = 0; ks < 4; ++ks)
      qf[mi][ks] = *(const short8*)(Qb + (size_t)(qrow0 + mi * 16 + lo) * QKVLD + ks * 32 + hi * 8);
#pragma unroll
  for (int mi = 0; mi < 2; ++mi) {
    float pos = (float)positions[b * 2048 + qrow0 + mi * 16 + lo];
#pragma unroll
    for (int ks = 0; ks < 2; ++ks)
#pragma unroll
      for (int j = 0; j < 8; ++j) {
        int d = ks * 32 + hi * 8 + j;      // in [0,64)
        float inv = exp2f((float)d * -0.2076205059304570f);
        float s, c;
        sincosf(pos * inv, &s, &c);
        float x1 = bf2f(qf[mi][ks][j]), x2 = bf2f(qf[mi][ks + 2][j]);
        qf[mi][ks][j]     = f2bf((x1 * c - x2 * s) * SEXP);
        qf[mi][ks + 2][j] = f2bf((x2 * c + x1 * s) * SEXP);
      }
  }

  f32x4 acc_o[2][9];
  float m_run[2][4];
#pragma unroll
  for (int mi = 0; mi < 2; ++mi) {
#pragma unroll
    for (int nf = 0; nf < 9; ++nf) acc_o[mi][nf] = (f32x4){0.f, 0.f, 0.f, 0.f};
#pragma unroll
    for (int r = 0; r < 4; ++r) m_run[mi][r] = -1e30f;
  }

  short8 vones;
#pragma unroll
  for (int j = 0; j < 8; ++j) vones[j] = (short)0x3F80;  // bf16 1.0

  const int nkv = (q0 + 128) >> 6;
  const int swz = (lo & 7) << 4;

  stage_kv(Kb, Vtb, 0, smem, smem + 16384, tid, wave);
  __syncthreads();

  int cur = 0;
  for (int kvt = 0; kvt < nkv; ++kvt) {
    const int kv0 = kvt << 6;
    if (kvt + 1 < nkv)
      stage_kv(Kb, Vtb, kv0 + 64, smem + (cur ^ 1) * 32768,
               smem + (cur ^ 1) * 32768 + 16384, tid, wave);

    if (kv0 <= qrow0 + 31) {
      const char* kl = smem + cur * 32768;
      const char* vl = smem + cur * 32768 + 16384;

      f32x4 accs[2][4];
#pragma unroll
      for (int mi = 0; mi < 2; ++mi)
#pragma unroll
        for (int nf = 0; nf < 4; ++nf) accs[mi][nf] = (f32x4){0.f, 0.f, 0.f, 0.f};
#pragma unroll
      for (int ks = 0; ks < 4; ++ks) {
        short8 kf[4];
#pragma unroll
        for (int nf = 0; nf < 4; ++nf) {
          int r = nf * 16 + lo;
          kf[nf] = *(const short8*)(kl + r * 256 + ((ks * 64 + hi * 16) ^ swz));
        }
        __builtin_amdgcn_s_setprio(1);
#pragma unroll
        for (int mi = 0; mi < 2; ++mi)
#pragma unroll
          for (int nf = 0; nf < 4; ++nf)
            accs[mi][nf] = __builtin_amdgcn_mfma_f32_16x16x32_bf16(qf[mi][ks], kf[nf], accs[mi][nf], 0, 0, 0);
        __builtin_amdgcn_s_setprio(0);
      }

      const bool needmask = (kv0 + 63 > qrow0);
      float pmax[2][4];
      bool okall = true;
#pragma unroll
      for (int mi = 0; mi < 2; ++mi) {
#pragma unroll
        for (int r = 0; r < 4; ++r) {
          const int qrow = qrow0 + mi * 16 + hi * 4 + r;
          if (needmask) {
#pragma unroll
            for (int nf = 0; nf < 4; ++nf) {
              int col = kv0 + nf * 16 + lo;
              accs[mi][nf][r] = (col <= qrow) ? accs[mi][nf][r] : -1e30f;
            }
          }
          float tmax = fmaxf(fmaxf(accs[mi][0][r], accs[mi][1][r]),
                             fmaxf(accs[mi][2][r], accs[mi][3][r]));
#pragma unroll
          for (int off = 1; off < 16; off <<= 1)
            tmax = fmaxf(tmax, __shfl_xor(tmax, off, 64));
          pmax[mi][r] = tmax;
          okall = okall && (tmax <= m_run[mi][r] + 8.0f);
        }
      }
      if (!__all(okall)) {
#pragma unroll
        for (int mi = 0; mi < 2; ++mi)
#pragma unroll
          for (int r = 0; r < 4; ++r) {
            float mnew = fmaxf(m_run[mi][r], pmax[mi][r]);
            float alpha = exp2f(m_run[mi][r] - mnew);
            m_run[mi][r] = mnew;
#pragma unroll
            for (int nf = 0; nf < 9; ++nf) acc_o[mi][nf][r] *= alpha;
          }
      }
#pragma unroll
      for (int mi = 0; mi < 2; ++mi)
#pragma unroll
        for (int r = 0; r < 4; ++r) {
          const int prow = mi * 16 + hi * 4 + r;
          const int psw = prow & 7;
#pragma unroll
          for (int nf = 0; nf < 4; ++nf) {
            float p = exp2f(accs[mi][nf][r] - m_run[mi][r]);
            int col = nf * 16 + lo;
            Pw[(prow << 6) + (((col >> 3) ^ psw) << 3) + (col & 7)] = f2bf(p);
          }
        }

#pragma unroll
      for (int ks = 0; ks < 2; ++ks) {
        short8 pf[2];
#pragma unroll
        for (int mi = 0; mi < 2; ++mi) {
          int prow = mi * 16 + lo;
          pf[mi] = *(const short8*)((const char*)Pw + prow * 128 + (((ks * 4 + hi) ^ (prow & 7)) << 4));
        }
        __builtin_amdgcn_s_setprio(1);
#pragma unroll
        for (int nf = 0; nf < 9; ++nf) {
          short8 vf;
          if (nf < 8) {
            int row = nf * 16 + lo;
            vf = *(const short8*)(vl + row * 128 + ((ks * 64 + hi * 16) ^ swz));
          } else {
            vf = vones;
          }
#pragma unroll
          for (int mi = 0; mi < 2; ++mi)
            acc_o[mi][nf] = __builtin_amdgcn_mfma_f32_16x16x32_bf16(pf[mi], vf, acc_o[mi][nf], 0, 0, 0);
        }
        __builtin_amdgcn_s_setprio(0);
      }
    }

    __syncthreads();
    cur ^= 1;
  }

  short* Osm = (short*)smem;   // [128][128]
#pragma unroll
  for (int mi = 0; mi < 2; ++mi)
#pragma unroll
    for (int r = 0; r < 4; ++r) {
      float inv = 1.0f / acc_o[mi][8][r];
      int row = wave * 32 + mi * 16 + hi * 4 + r;
#pragma unroll
      for (int nf = 0; nf < 8; ++nf)
        Osm[row * 128 + nf * 16 + lo] = f2bf(acc_o[mi][nf][r] * inv);
    }
  __syncthreads();
  short* Ob = base + h * Dh;
#pragma unroll
  for (int it = 0; it < 8; ++it) {
    int chunk = it * 256 + tid;
    int row = chunk >> 4, c8 = chunk & 15;
    *(short8*)(Ob + (size_t)(q0 + row) * QKVLD + c8 * 8) =
        *(const short8*)(Osm + row * 128 + c8 * 8);
  }
}

extern "C" void kernel_launch(void* const* d_in, const int* in_sizes, int n_in,
                              void* d_out, int out_size, void* d_ws, size_t ws_size,
                              hipStream_t stream) {
  const int*   positions = (const int*)d_in[0];
  const float* hidden    = (const float*)d_in[1];
  const float* w_pack    = (const float*)d_in[2];
  const float* w_o       = (const float*)d_in[3];
  float* out = (float*)d_out;

  char* ws = (char*)d_ws;
  short* Wpt  = (short*)ws;                                 // w_pack^T bf16 [12288][4096]
  short* qkvb = (short*)(ws + (size_t)12288 * 4096 * 2);    // qkv bf16 [4096][12288]
  short* Wot  = (short*)ws;                                 // w_o^T bf16 (reuses Wpt region)
  short* Hbf  = (short*)d_out;                              // hidden bf16 (d_out front 32MB)
  short* Vtg  = (short*)((char*)d_out + ((size_t)32 << 20)); // V^T bf16 (d_out back 32MB)

  // 1. hidden fp32 -> bf16 (dead after GEMM1)
  k_cvt<<<8192, 256, 0, stream>>>(hidden, Hbf, 4096 * 4096 / 8);
  // 2. w_pack^T bf16 (vectorized 64x64 transpose)
  k_tcvt64<<<dim3(12288 / 64, 4096 / 64), 256, 0, stream>>>(w_pack, Wpt, 4096, 12288);
  // 3. qkv = hidden @ w_pack  (256^2 tiles: grid 16 x 48 = 768, %8==0)
  k_gemm256<false><<<dim3(768), 512, 0, stream>>>(Hbf, 4096, Wpt, 4096, qkvb, QKVLD, 12288, 4096);
  // 4. RoPE on K only (Q-RoPE fused into k_attn)
  k_ropeK<<<4096, 256, 0, stream>>>(qkvb, positions);
  // 5. V^T into d_out back half (vectorized 64x64 transpose)
  k_vt64<<<dim3(64, 32, 2), 256, 0, stream>>>(qkvb, Vtg);
  // 6. attention (applies Q-RoPE in-register); O overwrites q region of qkv
  k_attn<<<dim3(1024), 256, 0, stream>>>(qkvb, Vtg, positions);
  // 7. w_o^T bf16 (Wpt region dead)
  k_tcvt64<<<dim3(4096 / 64, 4096 / 64), 256, 0, stream>>>(w_o, Wot, 4096, 4096);
  // 8. out = O @ w_o (fp32), overwrites all of d_out (grid 16 x 16 = 256)
  k_gemm256<true><<<dim3(256), 512, 0, stream>>>(qkvb, QKVLD, Wot, 4096, out, 4096, 4096, 4096);
}

// Round 13
// 766.066 us; speedup vs baseline: 1.0080x; 1.0080x over previous
//
#include <hip/hip_runtime.h>

// Problem constants
#define Sdim   2048
#define Hdim   4096
#define NHEADS 32
#define Dh     128
#define Mrows  4096      // B*S
#define QKVLD  12288     // 3*H

typedef __attribute__((ext_vector_type(8))) short short8;
typedef __attribute__((ext_vector_type(4))) float f32x4;
typedef __attribute__((ext_vector_type(4))) float float4v;

__device__ __forceinline__ short f2bf(float f) {
  union { float f; unsigned u; } x; x.f = f;
  unsigned r = x.u + 0x7fffu + ((x.u >> 16) & 1u);  // RNE
  return (short)(r >> 16);
}
__device__ __forceinline__ float bf2f(short s) {
  union { unsigned u; float f; } x; x.u = ((unsigned)(unsigned short)s) << 16;
  return x.f;
}

__device__ __forceinline__ void gload_lds16(const void* g, void* l) {
  __builtin_amdgcn_global_load_lds(
      (const __attribute__((address_space(1))) void*)g,
      (__attribute__((address_space(3))) void*)l, 16, 0, 0);
}

// ---------------- fp32 -> bf16 convert (8 elems/thread) ----------------
__global__ void k_cvt(const float* __restrict__ src, short* __restrict__ dst, int n8) {
  int idx = blockIdx.x * blockDim.x + threadIdx.x;
  if (idx >= n8) return;
  const float4v* s = (const float4v*)src + (size_t)idx * 2;
  float4v a = s[0], b = s[1];
  short8 o;
  o[0] = f2bf(a.x); o[1] = f2bf(a.y); o[2] = f2bf(a.z); o[3] = f2bf(a.w);
  o[4] = f2bf(b.x); o[5] = f2bf(b.y); o[6] = f2bf(b.z); o[7] = f2bf(b.w);
  *((short8*)dst + idx) = o;
}

// ---- transpose + convert, vectorized both sides: dst[C][R] bf16 = src[R][C] f32 ----
__global__ void k_tcvt64(const float* __restrict__ src, short* __restrict__ dst,
                         int R, int C) {
  __shared__ float t[64][65];
  const int tid = threadIdx.x;          // 256
  const int r0 = blockIdx.y * 64, c0 = blockIdx.x * 64;
  const int ir = tid >> 4, ic = (tid & 15) << 2;
#pragma unroll
  for (int p = 0; p < 4; ++p) {
    const float4v v = *(const float4v*)(src + (size_t)(r0 + p * 16 + ir) * C + c0 + ic);
    t[p * 16 + ir][ic] = v.x; t[p * 16 + ir][ic + 1] = v.y;
    t[p * 16 + ir][ic + 2] = v.z; t[p * 16 + ir][ic + 3] = v.w;
  }
  __syncthreads();
  const int oc = tid >> 3, orr = (tid & 7) << 3;
#pragma unroll
  for (int p = 0; p < 2; ++p) {
    int c = p * 32 + oc;
    short8 o;
#pragma unroll
    for (int j = 0; j < 8; ++j) o[j] = f2bf(t[orr + j][c]);
    *(short8*)(dst + (size_t)(c0 + c) * R + r0 + orr) = o;
  }
}

// ------- V transpose, vectorized: Vt[(b*32+h)*128+d][s] = qkv[b*2048+s][8192+hc] -------
__global__ void k_vt64(const short* __restrict__ qkv, short* __restrict__ vt) {
  __shared__ short tile[4096];  // [64 s][64 d] swizzled
  const int tid = threadIdx.x;          // 256
  const int c0 = blockIdx.x * 64;       // d-col base (0..4095)
  const int s0 = blockIdx.y * 64;       // token base within batch
  const int b  = blockIdx.z;
#pragma unroll
  for (int j = 0; j < 2; ++j) {
    int chunk = j * 256 + tid;
    int row = chunk >> 3, c8 = chunk & 7;
    short8 v = *(const short8*)(qkv + (size_t)(b * 2048 + s0 + row) * QKVLD + 8192 + c0 + c8 * 8);
    int sw = c8 ^ ((row ^ (row >> 3)) & 7);
    *(short8*)((char*)tile + row * 128 + sw * 16) = v;
  }
  __syncthreads();
#pragma unroll
  for (int j = 0; j < 2; ++j) {
    int chunk = j * 256 + tid;
    int d = chunk >> 3, s8 = (chunk & 7) << 3;
    short8 o;
#pragma unroll
    for (int j2 = 0; j2 < 8; ++j2) {
      int s = s8 + j2;
      int sw = ((d >> 3) ^ ((s ^ (s >> 3)) & 7));
      o[j2] = *(const short*)((const char*)tile + s * 128 + sw * 16 + (d & 7) * 2);
    }
    *(short8*)(vt + (size_t)(b * 4096 + c0 + d) * Sdim + s0 + s8) = o;
  }
}

// ============ 256x256-tile bf16 GEMM, 8 waves, 4 phases/K-tile, counted vmcnt ============
__device__ __forceinline__ void stage_half256(const short* G, int ld, int row0, int kcol,
                                              char* lds, int tid) {
#pragma unroll
  for (int j = 0; j < 2; ++j) {
    int p = j * 512 + tid;            // 16B chunk id in [0,1024): 8 chunks per 64-col row
    int r = p >> 3;
    int c = ((p & 7) ^ (r & 7)) << 3; // swizzled source column (elements)
    gload_lds16(G + (size_t)(row0 + r) * ld + kcol + c,
                lds + ((j * 512 + (tid & 448)) << 4));
  }
}

#define MFMA_Q(qm, qn)                                                                   \
  do {                                                                                   \
    __builtin_amdgcn_s_setprio(1);                                                       \
    _Pragma("unroll")                                                                    \
    for (int m4 = 0; m4 < 4; ++m4)                                                       \
      _Pragma("unroll")                                                                  \
      for (int n2 = 0; n2 < 2; ++n2) {                                                   \
        acc[(qm)*4+m4][(qn)*2+n2] = __builtin_amdgcn_mfma_f32_16x16x32_bf16(             \
            av[m4][0], bv[(qn)*2+n2][0], acc[(qm)*4+m4][(qn)*2+n2], 0, 0, 0);            \
        acc[(qm)*4+m4][(qn)*2+n2] = __builtin_amdgcn_mfma_f32_16x16x32_bf16(             \
            av[m4][1], bv[(qn)*2+n2][1], acc[(qm)*4+m4][(qn)*2+n2], 0, 0, 0);            \
      }                                                                                  \
    __builtin_amdgcn_s_setprio(0);                                                       \
  } while (0)

#define PH_BARRIER()                    \
  do {                                  \
    __builtin_amdgcn_s_barrier();       \
    __builtin_amdgcn_sched_barrier(0);  \
  } while (0)

template<bool C_F32>
__global__ __launch_bounds__(512, 2) void k_gemm256(const short* __restrict__ A, int lda,
                                                    const short* __restrict__ Bt, int ldb,
                                                    void* __restrict__ Cp, int ldc,
                                                    int Ndim, int Kdim) {
  __shared__ __align__(16) char smem[131072];
  const int tid  = threadIdx.x;
  const int lane = tid & 63;
  const int wave = tid >> 6;
  const int lo = lane & 15, hi = lane >> 4;
  const int wr = wave >> 2, wc = wave & 3;   // 2M x 4N waves; per-wave out 128x64

  // T1: XCD-aware bijective block swizzle (grid % 8 == 0 for all our calls)
  const int nblk = gridDim.x;
  const int lid = (blockIdx.x & 7) * (nblk >> 3) + (blockIdx.x >> 3);
  const int nbn = Ndim >> 8;
  const int bm0 = (lid / nbn) << 8;
  const int bn0 = (lid % nbn) << 8;

  f32x4 acc[8][4];
#pragma unroll
  for (int i = 0; i < 8; ++i)
#pragma unroll
    for (int j = 0; j < 4; ++j) acc[i][j] = (f32x4){0.f, 0.f, 0.f, 0.f};

  short8 av[4][2], bv[4][2];
  const int swz = (lo & 7) << 4;
  const int brow = (wc & 1) * 64;

  // prologue: K-tile 0 -> slot 0
  stage_half256(Bt, ldb, bn0,       0, smem + 32768,         tid);
  stage_half256(Bt, ldb, bn0 + 128, 0, smem + 32768 + 16384, tid);
  stage_half256(A,  lda, bm0,       0, smem,                 tid);
  stage_half256(A,  lda, bm0 + 128, 0, smem + 16384,         tid);

  const int NK = Kdim >> 6;
  for (int kt = 0; kt < NK; ++kt) {
    const int cur = kt & 1;
    const char* Ab = smem + cur * 65536 + wr * 16384;                 // wave's A half
    const char* Bb = smem + cur * 65536 + 32768 + (wc >> 1) * 16384;  // wave's B half
    char* nA = smem + (cur ^ 1) * 65536;
    char* nB = nA + 32768;
    const int kc = (kt + 1) << 6;
    const bool pf = (kt + 1 < NK);

    // ---- phase 0: stage B'h0+B'h1; counted drain; read A[0-3],B[0-1]; MFMA (0,0) ----
    if (pf) {
      stage_half256(Bt, ldb, bn0,       kc, nB,         tid);
      stage_half256(Bt, ldb, bn0 + 128, kc, nB + 16384, tid);
      asm volatile("s_waitcnt vmcnt(4)" ::: "memory");   // prev 8 landed; own 4 in flight
    } else {
      asm volatile("s_waitcnt vmcnt(0)" ::: "memory");   // final tile: full drain
    }
    PH_BARRIER();   // after this, slot cur is fully landed for ALL waves
#pragma unroll
    for (int m4 = 0; m4 < 4; ++m4)
#pragma unroll
      for (int ks = 0; ks < 2; ++ks)
        av[m4][ks] = *(const short8*)(Ab + (m4 * 16 + lo) * 128 + ((ks * 64 + hi * 16) ^ swz));
#pragma unroll
    for (int ni = 0; ni < 2; ++ni)
#pragma unroll
      for (int ks = 0; ks < 2; ++ks)
        bv[ni][ks] = *(const short8*)(Bb + (brow + ni * 16 + lo) * 128 + ((ks * 64 + hi * 16) ^ swz));
    MFMA_Q(0, 0);
    // hoisted reads for phase 1 (slot cur is landed)
#pragma unroll
    for (int ni = 2; ni < 4; ++ni)
#pragma unroll
      for (int ks = 0; ks < 2; ++ks)
        bv[ni][ks] = *(const short8*)(Bb + (brow + ni * 16 + lo) * 128 + ((ks * 64 + hi * 16) ^ swz));

    // ---- phase 1: stage A'h0+A'h1; MFMA (0,1); hoist A-rows 64-127 reads ----
    if (pf) {
      stage_half256(A, lda, bm0,       kc, nA,         tid);
      stage_half256(A, lda, bm0 + 128, kc, nA + 16384, tid);
    }
    PH_BARRIER();
    MFMA_Q(0, 1);
#pragma unroll
    for (int m4 = 0; m4 < 4; ++m4)
#pragma unroll
      for (int ks = 0; ks < 2; ++ks)
        av[m4][ks] = *(const short8*)(Ab + ((64 + m4 * 16 + lo) * 128) + ((ks * 64 + hi * 16) ^ swz));

    // ---- phase 2: MFMA (1,0) ----
    PH_BARRIER();
    MFMA_Q(1, 0);

    // ---- phase 3: MFMA (1,1) ----
    PH_BARRIER();
    MFMA_Q(1, 1);
  }

  // epilogue: C/D layout row=(lane>>4)*4+reg, col=lane&15
#pragma unroll
  for (int mi = 0; mi < 8; ++mi)
#pragma unroll
    for (int r = 0; r < 4; ++r) {
      int row = bm0 + wr * 128 + mi * 16 + hi * 4 + r;
#pragma unroll
      for (int ni = 0; ni < 4; ++ni) {
        int col = bn0 + wc * 64 + ni * 16 + lo;
        if (C_F32) ((float*)Cp)[(size_t)row * ldc + col] = acc[mi][ni][r];
        else       ((short*)Cp)[(size_t)row * ldc + col] = f2bf(acc[mi][ni][r]);
      }
    }
}

// ------------- RoPE in-place, vectorized: 8 consecutive d per thread (short8 x4) -------------
__global__ void k_rope8(short* qkv, const int* __restrict__ positions) {
  int idx = blockIdx.x * 256 + threadIdx.x;   // (row, h, t): 4096*32*8 threads
  int t = idx & 7;
  int h = (idx >> 3) & 31;
  int row = idx >> 8;
  float pos = (float)positions[row];
  size_t o = (size_t)row * QKVLD + h * 128 + t * 8;
  short8 q1 = *(short8*)(qkv + o),        q2 = *(short8*)(qkv + o + 64);
  short8 k1 = *(short8*)(qkv + o + 4096), k2 = *(short8*)(qkv + o + 4160);
#pragma unroll
  for (int j = 0; j < 8; ++j) {
    int d = t * 8 + j;
    float inv = exp2f((float)d * -0.2076205059304570f);
    float ang = pos * inv, s, c;
    sincosf(ang, &s, &c);
    float a1 = bf2f(q1[j]), a2 = bf2f(q2[j]);
    q1[j] = f2bf(a1 * c - a2 * s); q2[j] = f2bf(a2 * c + a1 * s);
    float b1 = bf2f(k1[j]), b2 = bf2f(k2[j]);
    k1[j] = f2bf(b1 * c - b2 * s); k2[j] = f2bf(b2 * c + b1 * s);
  }
  *(short8*)(qkv + o) = q1;        *(short8*)(qkv + o + 64) = q2;
  *(short8*)(qkv + o + 4096) = k1; *(short8*)(qkv + o + 4160) = k2;
}

// ---------------- causal flash attention (dbuf K/Vt, ones-column + defer-max) ----------------
// R13: R11 anchor + SEXP folded into Q fragments in-register (no sincos — 32 muls once
// per block) so the per-kv-tile "*SEXP" multiply is gone from the softmax loop.
__device__ __forceinline__ void stage_kv(const short* Kb, const short* Vtb, int kv0,
                                         char* kbuf, char* vbuf, int tid, int wave) {
#pragma unroll
  for (int i = 0; i < 4; ++i) {
    int p = i * 256 + tid;            // 16B chunk id in [0,1024)
    int r = p >> 4;                   // kv row (16 chunks/row)
    int c = (p & 15) ^ (r & 7);       // swizzled chunk within row
    gload_lds16(Kb + (size_t)(kv0 + r) * QKVLD + (c << 3),
                kbuf + ((i * 256 + wave * 64) << 4));
  }
#pragma unroll
  for (int i = 0; i < 4; ++i) {
    int p = i * 256 + tid;
    int r = p >> 3;                   // d row (8 chunks/row)
    int c = (p & 7) ^ (r & 7);        // swizzled chunk within row
    gload_lds16(Vtb + (size_t)r * Sdim + kv0 + (c << 3),
                vbuf + ((i * 256 + wave * 64) << 4));
  }
}

__global__ __launch_bounds__(256, 2) void k_attn(short* __restrict__ qkv,
                                                 const short* __restrict__ Vt) {
  __shared__ __align__(16) char smem[81920];
  const int tid  = threadIdx.x;
  const int lane = tid & 63;
  const int wave = tid >> 6;
  const int lo = lane & 15, hi = lane >> 4;

  const int bid = blockIdx.x;
  const int lid = (bid & 7) * 128 + (bid >> 3);
  const int bh = lid >> 4;
  const int qt = 15 - (lid & 15);     // heavy tiles first
  const int b = bh >> 5, h = bh & 31;
  const int q0 = qt << 7;

  short* base = qkv + (size_t)b * Sdim * QKVLD;
  const short* Qb = base + h * Dh;
  const short* Kb = base + Hdim + h * Dh;
  const short* Vtb = Vt + (size_t)(b * 32 + h) * 128 * Sdim;
  const int qrow0 = q0 + wave * 32;

  short* Pw = (short*)(smem + 65536 + wave * 4096);

  const float SEXP = 0.088388347648318447f * 1.4426950408889634f;  // scale*log2e

  // Q into registers (A-frag layout), then fold SEXP in-register (no sincos).
  short8 qf[2][4];
#pragma unroll
  for (int mi = 0; mi < 2; ++mi)
#pragma unroll
    for (int ks = 0; ks < 4; ++ks) {
      qf[mi][ks] = *(const short8*)(Qb + (size_t)(qrow0 + mi * 16 + lo) * QKVLD + ks * 32 + hi * 8);
#pragma unroll
      for (int j = 0; j < 8; ++j)
        qf[mi][ks][j] = f2bf(bf2f(qf[mi][ks][j]) * SEXP);
    }

  f32x4 acc_o[2][9];
  float m_run[2][4];
#pragma unroll
  for (int mi = 0; mi < 2; ++mi) {
#pragma unroll
    for (int nf = 0; nf < 9; ++nf) acc_o[mi][nf] = (f32x4){0.f, 0.f, 0.f, 0.f};
#pragma unroll
    for (int r = 0; r < 4; ++r) m_run[mi][r] = -1e30f;
  }

  short8 vones;
#pragma unroll
  for (int j = 0; j < 8; ++j) vones[j] = (short)0x3F80;  // bf16 1.0

  const int nkv = (q0 + 128) >> 6;
  const int swz = (lo & 7) << 4;

  stage_kv(Kb, Vtb, 0, smem, smem + 16384, tid, wave);
  __syncthreads();

  int cur = 0;
  for (int kvt = 0; kvt < nkv; ++kvt) {
    const int kv0 = kvt << 6;
    if (kvt + 1 < nkv)
      stage_kv(Kb, Vtb, kv0 + 64, smem + (cur ^ 1) * 32768,
               smem + (cur ^ 1) * 32768 + 16384, tid, wave);

    if (kv0 <= qrow0 + 31) {
      const char* kl = smem + cur * 32768;
      const char* vl = smem + cur * 32768 + 16384;

      f32x4 accs[2][4];
#pragma unroll
      for (int mi = 0; mi < 2; ++mi)
#pragma unroll
        for (int nf = 0; nf < 4; ++nf) accs[mi][nf] = (f32x4){0.f, 0.f, 0.f, 0.f};
#pragma unroll
      for (int ks = 0; ks < 4; ++ks) {
        short8 kf[4];
#pragma unroll
        for (int nf = 0; nf < 4; ++nf) {
          int r = nf * 16 + lo;
          kf[nf] = *(const short8*)(kl + r * 256 + ((ks * 64 + hi * 16) ^ swz));
        }
        __builtin_amdgcn_s_setprio(1);
#pragma unroll
        for (int mi = 0; mi < 2; ++mi)
#pragma unroll
          for (int nf = 0; nf < 4; ++nf)
            accs[mi][nf] = __builtin_amdgcn_mfma_f32_16x16x32_bf16(qf[mi][ks], kf[nf], accs[mi][nf], 0, 0, 0);
        __builtin_amdgcn_s_setprio(0);
      }

      const bool needmask = (kv0 + 63 > qrow0);
      float pmax[2][4];
      bool okall = true;
#pragma unroll
      for (int mi = 0; mi < 2; ++mi) {
#pragma unroll
        for (int r = 0; r < 4; ++r) {
          const int qrow = qrow0 + mi * 16 + hi * 4 + r;
          if (needmask) {
#pragma unroll
            for (int nf = 0; nf < 4; ++nf) {
              int col = kv0 + nf * 16 + lo;
              accs[mi][nf][r] = (col <= qrow) ? accs[mi][nf][r] : -1e30f;
            }
          }
          float tmax = fmaxf(fmaxf(accs[mi][0][r], accs[mi][1][r]),
                             fmaxf(accs[mi][2][r], accs[mi][3][r]));
#pragma unroll
          for (int off = 1; off < 16; off <<= 1)
            tmax = fmaxf(tmax, __shfl_xor(tmax, off, 64));
          pmax[mi][r] = tmax;
          okall = okall && (tmax <= m_run[mi][r] + 8.0f);
        }
      }
      if (!__all(okall)) {
#pragma unroll
        for (int mi = 0; mi < 2; ++mi)
#pragma unroll
          for (int r = 0; r < 4; ++r) {
            float mnew = fmaxf(m_run[mi][r], pmax[mi][r]);
            float alpha = exp2f(m_run[mi][r] - mnew);
            m_run[mi][r] = mnew;
#pragma unroll
            for (int nf = 0; nf < 9; ++nf) acc_o[mi][nf][r] *= alpha;
          }
      }
#pragma unroll
      for (int mi = 0; mi < 2; ++mi)
#pragma unroll
        for (int r = 0; r < 4; ++r) {
          const int prow = mi * 16 + hi * 4 + r;
          const int psw = prow & 7;
#pragma unroll
          for (int nf = 0; nf < 4; ++nf) {
            float p = exp2f(accs[mi][nf][r] - m_run[mi][r]);
            int col = nf * 16 + lo;
            Pw[(prow << 6) + (((col >> 3) ^ psw) << 3) + (col & 7)] = f2bf(p);
          }
        }

#pragma unroll
      for (int ks = 0; ks < 2; ++ks) {
        short8 pf[2];
#pragma unroll
        for (int mi = 0; mi < 2; ++mi) {
          int prow = mi * 16 + lo;
          pf[mi] = *(const short8*)((const char*)Pw + prow * 128 + (((ks * 4 + hi) ^ (prow & 7)) << 4));
        }
        __builtin_amdgcn_s_setprio(1);
#pragma unroll
        for (int nf = 0; nf < 9; ++nf) {
          short8 vf;
          if (nf < 8) {
            int row = nf * 16 + lo;
            vf = *(const short8*)(vl + row * 128 + ((ks * 64 + hi * 16) ^ swz));
          } else {
            vf = vones;
          }
#pragma unroll
          for (int mi = 0; mi < 2; ++mi)
            acc_o[mi][nf] = __builtin_amdgcn_mfma_f32_16x16x32_bf16(pf[mi], vf, acc_o[mi][nf], 0, 0, 0);
        }
        __builtin_amdgcn_s_setprio(0);
      }
    }

    __syncthreads();
    cur ^= 1;
  }

  short* Osm = (short*)smem;   // [128][128]
#pragma unroll
  for (int mi = 0; mi < 2; ++mi)
#pragma unroll
    for (int r = 0; r < 4; ++r) {
      float inv = 1.0f / acc_o[mi][8][r];
      int row = wave * 32 + mi * 16 + hi * 4 + r;
#pragma unroll
      for (int nf = 0; nf < 8; ++nf)
        Osm[row * 128 + nf * 16 + lo] = f2bf(acc_o[mi][nf][r] * inv);
    }
  __syncthreads();
  short* Ob = base + h * Dh;
#pragma unroll
  for (int it = 0; it < 8; ++it) {
    int chunk = it * 256 + tid;
    int row = chunk >> 4, c8 = chunk & 15;
    *(short8*)(Ob + (size_t)(q0 + row) * QKVLD + c8 * 8) =
        *(const short8*)(Osm + row * 128 + c8 * 8);
  }
}

extern "C" void kernel_launch(void* const* d_in, const int* in_sizes, int n_in,
                              void* d_out, int out_size, void* d_ws, size_t ws_size,
                              hipStream_t stream) {
  const int*   positions = (const int*)d_in[0];
  const float* hidden    = (const float*)d_in[1];
  const float* w_pack    = (const float*)d_in[2];
  const float* w_o       = (const float*)d_in[3];
  float* out = (float*)d_out;

  char* ws = (char*)d_ws;
  short* Wpt  = (short*)ws;                                 // w_pack^T bf16 [12288][4096]
  short* qkvb = (short*)(ws + (size_t)12288 * 4096 * 2);    // qkv bf16 [4096][12288]
  short* Wot  = (short*)ws;                                 // w_o^T bf16 (reuses Wpt region)
  short* Hbf  = (short*)d_out;                              // hidden bf16 (d_out front 32MB)
  short* Vtg  = (short*)((char*)d_out + ((size_t)32 << 20)); // V^T bf16 (d_out back 32MB)

  // 1. hidden fp32 -> bf16 (dead after GEMM1)
  k_cvt<<<8192, 256, 0, stream>>>(hidden, Hbf, 4096 * 4096 / 8);
  // 2. w_pack^T bf16 (vectorized 64x64 transpose)
  k_tcvt64<<<dim3(12288 / 64, 4096 / 64), 256, 0, stream>>>(w_pack, Wpt, 4096, 12288);
  // 3. qkv = hidden @ w_pack  (256^2 tiles: grid 16 x 48 = 768, %8==0)
  k_gemm256<false><<<dim3(768), 512, 0, stream>>>(Hbf, 4096, Wpt, 4096, qkvb, QKVLD, 12288, 4096);
  // 4. RoPE on q,k in place (vectorized)
  k_rope8<<<4096, 256, 0, stream>>>(qkvb, positions);
  // 5. V^T into d_out back half (vectorized 64x64 transpose)
  k_vt64<<<dim3(64, 32, 2), 256, 0, stream>>>(qkvb, Vtg);
  // 6. attention; O overwrites q region of qkv
  k_attn<<<dim3(1024), 256, 0, stream>>>(qkvb, Vtg);
  // 7. w_o^T bf16 (Wpt region dead)
  k_tcvt64<<<dim3(4096 / 64, 4096 / 64), 256, 0, stream>>>(w_o, Wot, 4096, 4096);
  // 8. out = O @ w_o (fp32), overwrites all of d_out (grid 16 x 16 = 256)
  k_gemm256<true><<<dim3(256), 512, 0, stream>>>(qkvb, QKVLD, Wot, 4096, out, 4096, 4096, 4096);
}

// Round 14
// 744.762 us; speedup vs baseline: 1.0368x; 1.0286x over previous
//
#include <hip/hip_runtime.h>

// Problem constants
#define Sdim   2048
#define Hdim   4096
#define NHEADS 32
#define Dh     128
#define Mrows  4096      // B*S
#define QKVLD  12288     // 3*H

typedef __attribute__((ext_vector_type(8))) short short8;
typedef __attribute__((ext_vector_type(4))) float f32x4;
typedef __attribute__((ext_vector_type(4))) float float4v;

__device__ __forceinline__ short f2bf(float f) {
  union { float f; unsigned u; } x; x.f = f;
  unsigned r = x.u + 0x7fffu + ((x.u >> 16) & 1u);  // RNE
  return (short)(r >> 16);
}
__device__ __forceinline__ float bf2f(short s) {
  union { unsigned u; float f; } x; x.u = ((unsigned)(unsigned short)s) << 16;
  return x.f;
}

__device__ __forceinline__ void gload_lds16(const void* g, void* l) {
  __builtin_amdgcn_global_load_lds(
      (const __attribute__((address_space(1))) void*)g,
      (__attribute__((address_space(3))) void*)l, 16, 0, 0);
}

// ---------------- fp32 -> bf16 convert (8 elems/thread) ----------------
__global__ void k_cvt(const float* __restrict__ src, short* __restrict__ dst, int n8) {
  int idx = blockIdx.x * blockDim.x + threadIdx.x;
  if (idx >= n8) return;
  const float4v* s = (const float4v*)src + (size_t)idx * 2;
  float4v a = s[0], b = s[1];
  short8 o;
  o[0] = f2bf(a.x); o[1] = f2bf(a.y); o[2] = f2bf(a.z); o[3] = f2bf(a.w);
  o[4] = f2bf(b.x); o[5] = f2bf(b.y); o[6] = f2bf(b.z); o[7] = f2bf(b.w);
  *((short8*)dst + idx) = o;
}

// ---- transpose + convert, vectorized both sides: dst[C][R] bf16 = src[R][C] f32 ----
__global__ void k_tcvt64(const float* __restrict__ src, short* __restrict__ dst,
                         int R, int C) {
  __shared__ float t[64][65];
  const int tid = threadIdx.x;          // 256
  const int r0 = blockIdx.y * 64, c0 = blockIdx.x * 64;
  const int ir = tid >> 4, ic = (tid & 15) << 2;
#pragma unroll
  for (int p = 0; p < 4; ++p) {
    const float4v v = *(const float4v*)(src + (size_t)(r0 + p * 16 + ir) * C + c0 + ic);
    t[p * 16 + ir][ic] = v.x; t[p * 16 + ir][ic + 1] = v.y;
    t[p * 16 + ir][ic + 2] = v.z; t[p * 16 + ir][ic + 3] = v.w;
  }
  __syncthreads();
  const int oc = tid >> 3, orr = (tid & 7) << 3;
#pragma unroll
  for (int p = 0; p < 2; ++p) {
    int c = p * 32 + oc;
    short8 o;
#pragma unroll
    for (int j = 0; j < 8; ++j) o[j] = f2bf(t[orr + j][c]);
    *(short8*)(dst + (size_t)(c0 + c) * R + r0 + orr) = o;
  }
}

// ============ 256x256-tile bf16 GEMM, 8 waves, 4 phases/K-tile, counted vmcnt ============
__device__ __forceinline__ void stage_half256(const short* G, int ld, int row0, int kcol,
                                              char* lds, int tid) {
#pragma unroll
  for (int j = 0; j < 2; ++j) {
    int p = j * 512 + tid;            // 16B chunk id in [0,1024): 8 chunks per 64-col row
    int r = p >> 3;
    int c = ((p & 7) ^ (r & 7)) << 3; // swizzled source column (elements)
    gload_lds16(G + (size_t)(row0 + r) * ld + kcol + c,
                lds + ((j * 512 + (tid & 448)) << 4));
  }
}

#define MFMA_Q(qm, qn)                                                                   \
  do {                                                                                   \
    __builtin_amdgcn_s_setprio(1);                                                       \
    _Pragma("unroll")                                                                    \
    for (int m4 = 0; m4 < 4; ++m4)                                                       \
      _Pragma("unroll")                                                                  \
      for (int n2 = 0; n2 < 2; ++n2) {                                                   \
        acc[(qm)*4+m4][(qn)*2+n2] = __builtin_amdgcn_mfma_f32_16x16x32_bf16(             \
            av[m4][0], bv[(qn)*2+n2][0], acc[(qm)*4+m4][(qn)*2+n2], 0, 0, 0);            \
        acc[(qm)*4+m4][(qn)*2+n2] = __builtin_amdgcn_mfma_f32_16x16x32_bf16(             \
            av[m4][1], bv[(qn)*2+n2][1], acc[(qm)*4+m4][(qn)*2+n2], 0, 0, 0);            \
      }                                                                                  \
    __builtin_amdgcn_s_setprio(0);                                                       \
  } while (0)

#define PH_BARRIER()                    \
  do {                                  \
    __builtin_amdgcn_s_barrier();       \
    __builtin_amdgcn_sched_barrier(0);  \
  } while (0)

template<bool C_F32>
__global__ __launch_bounds__(512, 2) void k_gemm256(const short* __restrict__ A, int lda,
                                                    const short* __restrict__ Bt, int ldb,
                                                    void* __restrict__ Cp, int ldc,
                                                    int Ndim, int Kdim) {
  __shared__ __align__(16) char smem[131072];
  const int tid  = threadIdx.x;
  const int lane = tid & 63;
  const int wave = tid >> 6;
  const int lo = lane & 15, hi = lane >> 4;
  const int wr = wave >> 2, wc = wave & 3;   // 2M x 4N waves; per-wave out 128x64

  // T1: XCD-aware bijective block swizzle (grid % 8 == 0 for all our calls)
  const int nblk = gridDim.x;
  const int lid = (blockIdx.x & 7) * (nblk >> 3) + (blockIdx.x >> 3);
  const int nbn = Ndim >> 8;
  const int bm0 = (lid / nbn) << 8;
  const int bn0 = (lid % nbn) << 8;

  f32x4 acc[8][4];
#pragma unroll
  for (int i = 0; i < 8; ++i)
#pragma unroll
    for (int j = 0; j < 4; ++j) acc[i][j] = (f32x4){0.f, 0.f, 0.f, 0.f};

  short8 av[4][2], bv[4][2];
  const int swz = (lo & 7) << 4;
  const int brow = (wc & 1) * 64;

  // prologue: K-tile 0 -> slot 0
  stage_half256(Bt, ldb, bn0,       0, smem + 32768,         tid);
  stage_half256(Bt, ldb, bn0 + 128, 0, smem + 32768 + 16384, tid);
  stage_half256(A,  lda, bm0,       0, smem,                 tid);
  stage_half256(A,  lda, bm0 + 128, 0, smem + 16384,         tid);

  const int NK = Kdim >> 6;
  for (int kt = 0; kt < NK; ++kt) {
    const int cur = kt & 1;
    const char* Ab = smem + cur * 65536 + wr * 16384;                 // wave's A half
    const char* Bb = smem + cur * 65536 + 32768 + (wc >> 1) * 16384;  // wave's B half
    char* nA = smem + (cur ^ 1) * 65536;
    char* nB = nA + 32768;
    const int kc = (kt + 1) << 6;
    const bool pf = (kt + 1 < NK);

    // ---- phase 0: stage B'h0+B'h1; counted drain; read A[0-3],B[0-1]; MFMA (0,0) ----
    if (pf) {
      stage_half256(Bt, ldb, bn0,       kc, nB,         tid);
      stage_half256(Bt, ldb, bn0 + 128, kc, nB + 16384, tid);
      asm volatile("s_waitcnt vmcnt(4)" ::: "memory");   // prev 8 landed; own 4 in flight
    } else {
      asm volatile("s_waitcnt vmcnt(0)" ::: "memory");   // final tile: full drain
    }
    PH_BARRIER();   // after this, slot cur is fully landed for ALL waves
#pragma unroll
    for (int m4 = 0; m4 < 4; ++m4)
#pragma unroll
      for (int ks = 0; ks < 2; ++ks)
        av[m4][ks] = *(const short8*)(Ab + (m4 * 16 + lo) * 128 + ((ks * 64 + hi * 16) ^ swz));
#pragma unroll
    for (int ni = 0; ni < 2; ++ni)
#pragma unroll
      for (int ks = 0; ks < 2; ++ks)
        bv[ni][ks] = *(const short8*)(Bb + (brow + ni * 16 + lo) * 128 + ((ks * 64 + hi * 16) ^ swz));
    MFMA_Q(0, 0);
    // hoisted reads for phase 1 (slot cur is landed)
#pragma unroll
    for (int ni = 2; ni < 4; ++ni)
#pragma unroll
      for (int ks = 0; ks < 2; ++ks)
        bv[ni][ks] = *(const short8*)(Bb + (brow + ni * 16 + lo) * 128 + ((ks * 64 + hi * 16) ^ swz));

    // ---- phase 1: stage A'h0+A'h1; MFMA (0,1); hoist A-rows 64-127 reads ----
    if (pf) {
      stage_half256(A, lda, bm0,       kc, nA,         tid);
      stage_half256(A, lda, bm0 + 128, kc, nA + 16384, tid);
    }
    PH_BARRIER();
    MFMA_Q(0, 1);
#pragma unroll
    for (int m4 = 0; m4 < 4; ++m4)
#pragma unroll
      for (int ks = 0; ks < 2; ++ks)
        av[m4][ks] = *(const short8*)(Ab + ((64 + m4 * 16 + lo) * 128) + ((ks * 64 + hi * 16) ^ swz));

    // ---- phase 2: MFMA (1,0) ----
    PH_BARRIER();
    MFMA_Q(1, 0);

    // ---- phase 3: MFMA (1,1) ----
    PH_BARRIER();
    MFMA_Q(1, 1);
  }

  // epilogue: C/D layout row=(lane>>4)*4+reg, col=lane&15
#pragma unroll
  for (int mi = 0; mi < 8; ++mi)
#pragma unroll
    for (int r = 0; r < 4; ++r) {
      int row = bm0 + wr * 128 + mi * 16 + hi * 4 + r;
#pragma unroll
      for (int ni = 0; ni < 4; ++ni) {
        int col = bn0 + wc * 64 + ni * 16 + lo;
        if (C_F32) ((float*)Cp)[(size_t)row * ldc + col] = acc[mi][ni][r];
        else       ((short*)Cp)[(size_t)row * ldc + col] = f2bf(acc[mi][ni][r]);
      }
    }
}

// ---- fused RoPE (blocks 0..4095) + V-transpose (blocks 4096..8191), disjoint regions ----
__global__ void k_ropevt(short* __restrict__ qkv, const int* __restrict__ positions,
                         short* __restrict__ vt) {
  __shared__ short tile[4096];
  const int bid = blockIdx.x;
  const int tid = threadIdx.x;
  if (bid < 4096) {
    // RoPE on q,k (same as proven k_rope8)
    int idx = bid * 256 + tid;
    int t = idx & 7;
    int h = (idx >> 3) & 31;
    int row = idx >> 8;
    float pos = (float)positions[row];
    size_t o = (size_t)row * QKVLD + h * 128 + t * 8;
    short8 q1 = *(short8*)(qkv + o),        q2 = *(short8*)(qkv + o + 64);
    short8 k1 = *(short8*)(qkv + o + 4096), k2 = *(short8*)(qkv + o + 4160);
#pragma unroll
    for (int j = 0; j < 8; ++j) {
      int d = t * 8 + j;
      float inv = exp2f((float)d * -0.2076205059304570f);
      float ang = pos * inv, s, c;
      sincosf(ang, &s, &c);
      float a1 = bf2f(q1[j]), a2 = bf2f(q2[j]);
      q1[j] = f2bf(a1 * c - a2 * s); q2[j] = f2bf(a2 * c + a1 * s);
      float b1 = bf2f(k1[j]), b2 = bf2f(k2[j]);
      k1[j] = f2bf(b1 * c - b2 * s); k2[j] = f2bf(b2 * c + b1 * s);
    }
    *(short8*)(qkv + o) = q1;        *(short8*)(qkv + o + 64) = q2;
    *(short8*)(qkv + o + 4096) = k1; *(short8*)(qkv + o + 4160) = k2;
  } else {
    // V transpose (same as proven k_vt64); idx -> (x, y, z) of dim3(64, 32, 2)
    int idx = bid - 4096;
    const int c0 = (idx & 63) << 6;
    const int s0 = ((idx >> 6) & 31) << 6;
    const int b  = idx >> 11;
#pragma unroll
    for (int j = 0; j < 2; ++j) {
      int chunk = j * 256 + tid;
      int row = chunk >> 3, c8 = chunk & 7;
      short8 v = *(const short8*)(qkv + (size_t)(b * 2048 + s0 + row) * QKVLD + 8192 + c0 + c8 * 8);
      int sw = c8 ^ ((row ^ (row >> 3)) & 7);
      *(short8*)((char*)tile + row * 128 + sw * 16) = v;
    }
    __syncthreads();
#pragma unroll
    for (int j = 0; j < 2; ++j) {
      int chunk = j * 256 + tid;
      int d = chunk >> 3, s8 = (chunk & 7) << 3;
      short8 o;
#pragma unroll
      for (int j2 = 0; j2 < 8; ++j2) {
        int s = s8 + j2;
        int sw = ((d >> 3) ^ ((s ^ (s >> 3)) & 7));
        o[j2] = *(const short*)((const char*)tile + s * 128 + sw * 16 + (d & 7) * 2);
      }
      *(short8*)(vt + (size_t)(b * 4096 + c0 + d) * Sdim + s0 + s8) = o;
    }
  }
}

// ---------------- causal flash attention + piggybacked w_o^T transpose ----------------
// blocks 0..1023: attention (unchanged proven structure, XCD-swizzled).
// blocks 1024..5119: w_o 64x64 transpose-convert (independent data; overlaps the
// attn dispatch's unused HBM bandwidth and backfills its load-imbalanced tail).
__device__ __forceinline__ void stage_kv(const short* Kb, const short* Vtb, int kv0,
                                         char* kbuf, char* vbuf, int tid, int wave) {
#pragma unroll
  for (int i = 0; i < 4; ++i) {
    int p = i * 256 + tid;            // 16B chunk id in [0,1024)
    int r = p >> 4;                   // kv row (16 chunks/row)
    int c = (p & 15) ^ (r & 7);       // swizzled chunk within row
    gload_lds16(Kb + (size_t)(kv0 + r) * QKVLD + (c << 3),
                kbuf + ((i * 256 + wave * 64) << 4));
  }
#pragma unroll
  for (int i = 0; i < 4; ++i) {
    int p = i * 256 + tid;
    int r = p >> 3;                   // d row (8 chunks/row)
    int c = (p & 7) ^ (r & 7);        // swizzled chunk within row
    gload_lds16(Vtb + (size_t)r * Sdim + kv0 + (c << 3),
                vbuf + ((i * 256 + wave * 64) << 4));
  }
}

__global__ __launch_bounds__(256, 2) void k_attn(short* __restrict__ qkv,
                                                 const short* __restrict__ Vt,
                                                 const float* __restrict__ w_o,
                                                 short* __restrict__ Wot) {
  __shared__ __align__(16) char smem[81920];
  const int tid  = threadIdx.x;

  if (blockIdx.x >= 1024) {
    // ---- piggybacked w_o^T (64x64 tile, proven k_tcvt64 body; R=C=4096) ----
    float (*t)[65] = (float(*)[65])smem;   // 16.6 KB of the 80 KB
    const int idx = blockIdx.x - 1024;     // 4096 blocks = 64 x 64 tiles
    const int c0 = (idx & 63) << 6, r0 = (idx >> 6) << 6;
    const int ir = tid >> 4, ic = (tid & 15) << 2;
#pragma unroll
    for (int p = 0; p < 4; ++p) {
      const float4v v = *(const float4v*)(w_o + (size_t)(r0 + p * 16 + ir) * 4096 + c0 + ic);
      t[p * 16 + ir][ic] = v.x; t[p * 16 + ir][ic + 1] = v.y;
      t[p * 16 + ir][ic + 2] = v.z; t[p * 16 + ir][ic + 3] = v.w;
    }
    __syncthreads();
    const int oc = tid >> 3, orr = (tid & 7) << 3;
#pragma unroll
    for (int p = 0; p < 2; ++p) {
      int c = p * 32 + oc;
      short8 o;
#pragma unroll
      for (int j = 0; j < 8; ++j) o[j] = f2bf(t[orr + j][c]);
      *(short8*)(Wot + (size_t)(c0 + c) * 4096 + r0 + orr) = o;
    }
    return;
  }

  const int lane = tid & 63;
  const int wave = tid >> 6;
  const int lo = lane & 15, hi = lane >> 4;

  const int bid = blockIdx.x;
  const int lid = (bid & 7) * 128 + (bid >> 3);
  const int bh = lid >> 4;
  const int qt = 15 - (lid & 15);     // heavy tiles first
  const int b = bh >> 5, h = bh & 31;
  const int q0 = qt << 7;

  short* base = qkv + (size_t)b * Sdim * QKVLD;
  const short* Qb = base + h * Dh;
  const short* Kb = base + Hdim + h * Dh;
  const short* Vtb = Vt + (size_t)(b * 32 + h) * 128 * Sdim;
  const int qrow0 = q0 + wave * 32;

  short* Pw = (short*)(smem + 65536 + wave * 4096);

  const float SEXP = 0.088388347648318447f * 1.4426950408889634f;  // scale*log2e

  // Q into registers (A-frag layout), SEXP folded in-register.
  short8 qf[2][4];
#pragma unroll
  for (int mi = 0; mi < 2; ++mi)
#pragma unroll
    for (int ks = 0; ks < 4; ++ks) {
      qf[mi][ks] = *(const short8*)(Qb + (size_t)(qrow0 + mi * 16 + lo) * QKVLD + ks * 32 + hi * 8);
#pragma unroll
      for (int j = 0; j < 8; ++j)
        qf[mi][ks][j] = f2bf(bf2f(qf[mi][ks][j]) * SEXP);
    }

  f32x4 acc_o[2][9];
  float m_run[2][4];
#pragma unroll
  for (int mi = 0; mi < 2; ++mi) {
#pragma unroll
    for (int nf = 0; nf < 9; ++nf) acc_o[mi][nf] = (f32x4){0.f, 0.f, 0.f, 0.f};
#pragma unroll
    for (int r = 0; r < 4; ++r) m_run[mi][r] = -1e30f;
  }

  short8 vones;
#pragma unroll
  for (int j = 0; j < 8; ++j) vones[j] = (short)0x3F80;  // bf16 1.0

  const int nkv = (q0 + 128) >> 6;
  const int swz = (lo & 7) << 4;

  stage_kv(Kb, Vtb, 0, smem, smem + 16384, tid, wave);
  __syncthreads();

  int cur = 0;
  for (int kvt = 0; kvt < nkv; ++kvt) {
    const int kv0 = kvt << 6;
    if (kvt + 1 < nkv)
      stage_kv(Kb, Vtb, kv0 + 64, smem + (cur ^ 1) * 32768,
               smem + (cur ^ 1) * 32768 + 16384, tid, wave);

    if (kv0 <= qrow0 + 31) {
      const char* kl = smem + cur * 32768;
      const char* vl = smem + cur * 32768 + 16384;

      f32x4 accs[2][4];
#pragma unroll
      for (int mi = 0; mi < 2; ++mi)
#pragma unroll
        for (int nf = 0; nf < 4; ++nf) accs[mi][nf] = (f32x4){0.f, 0.f, 0.f, 0.f};
#pragma unroll
      for (int ks = 0; ks < 4; ++ks) {
        short8 kf[4];
#pragma unroll
        for (int nf = 0; nf < 4; ++nf) {
          int r = nf * 16 + lo;
          kf[nf] = *(const short8*)(kl + r * 256 + ((ks * 64 + hi * 16) ^ swz));
        }
        __builtin_amdgcn_s_setprio(1);
#pragma unroll
        for (int mi = 0; mi < 2; ++mi)
#pragma unroll
          for (int nf = 0; nf < 4; ++nf)
            accs[mi][nf] = __builtin_amdgcn_mfma_f32_16x16x32_bf16(qf[mi][ks], kf[nf], accs[mi][nf], 0, 0, 0);
        __builtin_amdgcn_s_setprio(0);
      }

      const bool needmask = (kv0 + 63 > qrow0);
      float pmax[2][4];
      bool okall = true;
#pragma unroll
      for (int mi = 0; mi < 2; ++mi) {
#pragma unroll
        for (int r = 0; r < 4; ++r) {
          const int qrow = qrow0 + mi * 16 + hi * 4 + r;
          if (needmask) {
#pragma unroll
            for (int nf = 0; nf < 4; ++nf) {
              int col = kv0 + nf * 16 + lo;
              accs[mi][nf][r] = (col <= qrow) ? accs[mi][nf][r] : -1e30f;
            }
          }
          float tmax = fmaxf(fmaxf(accs[mi][0][r], accs[mi][1][r]),
                             fmaxf(accs[mi][2][r], accs[mi][3][r]));
#pragma unroll
          for (int off = 1; off < 16; off <<= 1)
            tmax = fmaxf(tmax, __shfl_xor(tmax, off, 64));
          pmax[mi][r] = tmax;
          okall = okall && (tmax <= m_run[mi][r] + 8.0f);
        }
      }
      if (!__all(okall)) {
#pragma unroll
        for (int mi = 0; mi < 2; ++mi)
#pragma unroll
          for (int r = 0; r < 4; ++r) {
            float mnew = fmaxf(m_run[mi][r], pmax[mi][r]);
            float alpha = exp2f(m_run[mi][r] - mnew);
            m_run[mi][r] = mnew;
#pragma unroll
            for (int nf = 0; nf < 9; ++nf) acc_o[mi][nf][r] *= alpha;
          }
      }
#pragma unroll
      for (int mi = 0; mi < 2; ++mi)
#pragma unroll
        for (int r = 0; r < 4; ++r) {
          const int prow = mi * 16 + hi * 4 + r;
          const int psw = prow & 7;
#pragma unroll
          for (int nf = 0; nf < 4; ++nf) {
            float p = exp2f(accs[mi][nf][r] - m_run[mi][r]);
            int col = nf * 16 + lo;
            Pw[(prow << 6) + (((col >> 3) ^ psw) << 3) + (col & 7)] = f2bf(p);
          }
        }

#pragma unroll
      for (int ks = 0; ks < 2; ++ks) {
        short8 pf[2];
#pragma unroll
        for (int mi = 0; mi < 2; ++mi) {
          int prow = mi * 16 + lo;
          pf[mi] = *(const short8*)((const char*)Pw + prow * 128 + (((ks * 4 + hi) ^ (prow & 7)) << 4));
        }
        __builtin_amdgcn_s_setprio(1);
#pragma unroll
        for (int nf = 0; nf < 9; ++nf) {
          short8 vf;
          if (nf < 8) {
            int row = nf * 16 + lo;
            vf = *(const short8*)(vl + row * 128 + ((ks * 64 + hi * 16) ^ swz));
          } else {
            vf = vones;
          }
#pragma unroll
          for (int mi = 0; mi < 2; ++mi)
            acc_o[mi][nf] = __builtin_amdgcn_mfma_f32_16x16x32_bf16(pf[mi], vf, acc_o[mi][nf], 0, 0, 0);
        }
        __builtin_amdgcn_s_setprio(0);
      }
    }

    __syncthreads();
    cur ^= 1;
  }

  short* Osm = (short*)smem;   // [128][128]
#pragma unroll
  for (int mi = 0; mi < 2; ++mi)
#pragma unroll
    for (int r = 0; r < 4; ++r) {
      float inv = 1.0f / acc_o[mi][8][r];
      int row = wave * 32 + mi * 16 + hi * 4 + r;
#pragma unroll
      for (int nf = 0; nf < 8; ++nf)
        Osm[row * 128 + nf * 16 + lo] = f2bf(acc_o[mi][nf][r] * inv);
    }
  __syncthreads();
  short* Ob = base + h * Dh;
#pragma unroll
  for (int it = 0; it < 8; ++it) {
    int chunk = it * 256 + tid;
    int row = chunk >> 4, c8 = chunk & 15;
    *(short8*)(Ob + (size_t)(q0 + row) * QKVLD + c8 * 8) =
        *(const short8*)(Osm + row * 128 + c8 * 8);
  }
}

extern "C" void kernel_launch(void* const* d_in, const int* in_sizes, int n_in,
                              void* d_out, int out_size, void* d_ws, size_t ws_size,
                              hipStream_t stream) {
  const int*   positions = (const int*)d_in[0];
  const float* hidden    = (const float*)d_in[1];
  const float* w_pack    = (const float*)d_in[2];
  const float* w_o       = (const float*)d_in[3];
  float* out = (float*)d_out;

  char* ws = (char*)d_ws;
  short* Wpt  = (short*)ws;                                 // w_pack^T bf16 [12288][4096]
  short* qkvb = (short*)(ws + (size_t)12288 * 4096 * 2);    // qkv bf16 [4096][12288]
  short* Wot  = (short*)ws;                                 // w_o^T bf16 (reuses Wpt region)
  short* Hbf  = (short*)d_out;                              // hidden bf16 (d_out front 32MB)
  short* Vtg  = (short*)((char*)d_out + ((size_t)32 << 20)); // V^T bf16 (d_out back 32MB)

  // 1. hidden fp32 -> bf16 (dead after GEMM1)
  k_cvt<<<8192, 256, 0, stream>>>(hidden, Hbf, 4096 * 4096 / 8);
  // 2. w_pack^T bf16 (vectorized 64x64 transpose)
  k_tcvt64<<<dim3(12288 / 64, 4096 / 64), 256, 0, stream>>>(w_pack, Wpt, 4096, 12288);
  // 3. qkv = hidden @ w_pack  (256^2 tiles: grid 16 x 48 = 768, %8==0)
  k_gemm256<false><<<dim3(768), 512, 0, stream>>>(Hbf, 4096, Wpt, 4096, qkvb, QKVLD, 12288, 4096);
  // 4. RoPE (q,k) + V^T, fused single dispatch (disjoint qkv regions)
  k_ropevt<<<8192, 256, 0, stream>>>(qkvb, positions, Vtg);
  // 5. attention (blocks 0..1023) + piggybacked w_o^T (blocks 1024..5119)
  k_attn<<<dim3(5120), 256, 0, stream>>>(qkvb, Vtg, w_o, Wot);
  // 6. out = O @ w_o (fp32), overwrites all of d_out (grid 16 x 16 = 256)
  k_gemm256<true><<<dim3(256), 512, 0, stream>>>(qkvb, QKVLD, Wot, 4096, out, 4096, 4096, 4096);
}

// Round 15
// 728.844 us; speedup vs baseline: 1.0595x; 1.0218x over previous
//
#include <hip/hip_runtime.h>

// Problem constants
#define Sdim   2048
#define Hdim   4096
#define NHEADS 32
#define Dh     128
#define Mrows  4096      // B*S
#define QKVLD  12288     // 3*H

typedef __attribute__((ext_vector_type(8))) short short8;
typedef __attribute__((ext_vector_type(4))) short short4v;
typedef __attribute__((ext_vector_type(4))) float f32x4;
typedef __attribute__((ext_vector_type(4))) float float4v;

__device__ __forceinline__ short f2bf(float f) {
  union { float f; unsigned u; } x; x.f = f;
  unsigned r = x.u + 0x7fffu + ((x.u >> 16) & 1u);  // RNE
  return (short)(r >> 16);
}
__device__ __forceinline__ float bf2f(short s) {
  union { unsigned u; float f; } x; x.u = ((unsigned)(unsigned short)s) << 16;
  return x.f;
}

__device__ __forceinline__ void gload_lds16(const void* g, void* l) {
  __builtin_amdgcn_global_load_lds(
      (const __attribute__((address_space(1))) void*)g,
      (__attribute__((address_space(3))) void*)l, 16, 0, 0);
}

// ---------------- fp32 -> bf16 convert (8 elems/thread) ----------------
__global__ void k_cvt(const float* __restrict__ src, short* __restrict__ dst, int n8) {
  int idx = blockIdx.x * blockDim.x + threadIdx.x;
  if (idx >= n8) return;
  const float4v* s = (const float4v*)src + (size_t)idx * 2;
  float4v a = s[0], b = s[1];
  short8 o;
  o[0] = f2bf(a.x); o[1] = f2bf(a.y); o[2] = f2bf(a.z); o[3] = f2bf(a.w);
  o[4] = f2bf(b.x); o[5] = f2bf(b.y); o[6] = f2bf(b.z); o[7] = f2bf(b.w);
  *((short8*)dst + idx) = o;
}

// ---- transpose + convert, vectorized both sides: dst[C][R] bf16 = src[R][C] f32 ----
__global__ void k_tcvt64(const float* __restrict__ src, short* __restrict__ dst,
                         int R, int C) {
  __shared__ float t[64][65];
  const int tid = threadIdx.x;          // 256
  const int r0 = blockIdx.y * 64, c0 = blockIdx.x * 64;
  const int ir = tid >> 4, ic = (tid & 15) << 2;
#pragma unroll
  for (int p = 0; p < 4; ++p) {
    const float4v v = *(const float4v*)(src + (size_t)(r0 + p * 16 + ir) * C + c0 + ic);
    t[p * 16 + ir][ic] = v.x; t[p * 16 + ir][ic + 1] = v.y;
    t[p * 16 + ir][ic + 2] = v.z; t[p * 16 + ir][ic + 3] = v.w;
  }
  __syncthreads();
  const int oc = tid >> 3, orr = (tid & 7) << 3;
#pragma unroll
  for (int p = 0; p < 2; ++p) {
    int c = p * 32 + oc;
    short8 o;
#pragma unroll
    for (int j = 0; j < 8; ++j) o[j] = f2bf(t[orr + j][c]);
    *(short8*)(dst + (size_t)(c0 + c) * R + r0 + orr) = o;
  }
}

// ============ 256x256-tile bf16 GEMM, 8 waves, 4 phases/K-tile, counted vmcnt ============
// R15: B-fragment column remap col = bn0 + wc*16 + ni*64 + lo (traffic-neutral; row&7
// still == lo&7 so the stage/read swizzle is unchanged). This puts RoPE pairs (d, d+64)
// in-register: acc[mi][0/1] and acc[mi][2/3]. MODE 1 epilogue ropes q/k in fp32 and
// emits V^T directly (V-blocks skip the qkv store — nothing reads qkv's V region).
__device__ __forceinline__ void stage_half256(const short* G, int ld, int row0, int kcol,
                                              char* lds, int tid) {
#pragma unroll
  for (int j = 0; j < 2; ++j) {
    int p = j * 512 + tid;            // 16B chunk id in [0,1024): 8 chunks per 64-col row
    int r = p >> 3;
    int c = ((p & 7) ^ (r & 7)) << 3; // swizzled source column (elements)
    gload_lds16(G + (size_t)(row0 + r) * ld + kcol + c,
                lds + ((j * 512 + (tid & 448)) << 4));
  }
}

#define MFMA_Q(qm, qn)                                                                   \
  do {                                                                                   \
    __builtin_amdgcn_s_setprio(1);                                                       \
    _Pragma("unroll")                                                                    \
    for (int m4 = 0; m4 < 4; ++m4)                                                       \
      _Pragma("unroll")                                                                  \
      for (int n2 = 0; n2 < 2; ++n2) {                                                   \
        acc[(qm)*4+m4][(qn)*2+n2] = __builtin_amdgcn_mfma_f32_16x16x32_bf16(             \
            av[m4][0], bv[(qn)*2+n2][0], acc[(qm)*4+m4][(qn)*2+n2], 0, 0, 0);            \
        acc[(qm)*4+m4][(qn)*2+n2] = __builtin_amdgcn_mfma_f32_16x16x32_bf16(             \
            av[m4][1], bv[(qn)*2+n2][1], acc[(qm)*4+m4][(qn)*2+n2], 0, 0, 0);            \
      }                                                                                  \
    __builtin_amdgcn_s_setprio(0);                                                       \
  } while (0)

#define PH_BARRIER()                    \
  do {                                  \
    __builtin_amdgcn_s_barrier();       \
    __builtin_amdgcn_sched_barrier(0);  \
  } while (0)

template<int MODE>  // 0: fp32 direct store; 1: fused qkv epilogue (rope q/k, V^T emit)
__global__ __launch_bounds__(512, 2) void k_gemm256(const short* __restrict__ A, int lda,
                                                    const short* __restrict__ Bt, int ldb,
                                                    void* __restrict__ Cp, int ldc,
                                                    int Ndim, int Kdim,
                                                    const int* __restrict__ positions,
                                                    short* __restrict__ Vtg) {
  __shared__ __align__(16) char smem[131072];
  const int tid  = threadIdx.x;
  const int lane = tid & 63;
  const int wave = tid >> 6;
  const int lo = lane & 15, hi = lane >> 4;
  const int wr = wave >> 2, wc = wave & 3;   // 2M x 4N waves; per-wave out 128x64

  // T1: XCD-aware bijective block swizzle (grid % 8 == 0 for all our calls)
  const int nblk = gridDim.x;
  const int lid = (blockIdx.x & 7) * (nblk >> 3) + (blockIdx.x >> 3);
  const int nbn = Ndim >> 8;
  const int bm0 = (lid / nbn) << 8;
  const int bn0 = (lid % nbn) << 8;

  f32x4 acc[8][4];
#pragma unroll
  for (int i = 0; i < 8; ++i)
#pragma unroll
    for (int j = 0; j < 4; ++j) acc[i][j] = (f32x4){0.f, 0.f, 0.f, 0.f};

  short8 av[4][2], bv[4][2];
  const int swz = (lo & 7) << 4;

  // prologue: K-tile 0 -> slot 0
  stage_half256(Bt, ldb, bn0,       0, smem + 32768,         tid);
  stage_half256(Bt, ldb, bn0 + 128, 0, smem + 32768 + 16384, tid);
  stage_half256(A,  lda, bm0,       0, smem,                 tid);
  stage_half256(A,  lda, bm0 + 128, 0, smem + 16384,         tid);

  const int NK = Kdim >> 6;
  for (int kt = 0; kt < NK; ++kt) {
    const int cur = kt & 1;
    const char* Ab = smem + cur * 65536 + wr * 16384;   // wave's A half (128 rows)
    const char* Bb = smem + cur * 65536 + 32768;        // full B tile (256 rows)
    char* nA = smem + (cur ^ 1) * 65536;
    char* nB = nA + 32768;
    const int kc = (kt + 1) << 6;
    const bool pf = (kt + 1 < NK);

    // ---- phase 0: stage B'h0+B'h1; counted drain; read A[0-3],B[0-1]; MFMA (0,0) ----
    if (pf) {
      stage_half256(Bt, ldb, bn0,       kc, nB,         tid);
      stage_half256(Bt, ldb, bn0 + 128, kc, nB + 16384, tid);
      asm volatile("s_waitcnt vmcnt(4)" ::: "memory");   // prev 8 landed; own 4 in flight
    } else {
      asm volatile("s_waitcnt vmcnt(0)" ::: "memory");   // final tile: full drain
    }
    PH_BARRIER();   // after this, slot cur is fully landed for ALL waves
#pragma unroll
    for (int m4 = 0; m4 < 4; ++m4)
#pragma unroll
      for (int ks = 0; ks < 2; ++ks)
        av[m4][ks] = *(const short8*)(Ab + (m4 * 16 + lo) * 128 + ((ks * 64 + hi * 16) ^ swz));
#pragma unroll
    for (int ni = 0; ni < 2; ++ni)
#pragma unroll
      for (int ks = 0; ks < 2; ++ks)
        bv[ni][ks] = *(const short8*)(Bb + (wc * 16 + ni * 64 + lo) * 128 + ((ks * 64 + hi * 16) ^ swz));
    MFMA_Q(0, 0);
    // hoisted reads for phase 1 (slot cur is landed)
#pragma unroll
    for (int ni = 2; ni < 4; ++ni)
#pragma unroll
      for (int ks = 0; ks < 2; ++ks)
        bv[ni][ks] = *(const short8*)(Bb + (wc * 16 + ni * 64 + lo) * 128 + ((ks * 64 + hi * 16) ^ swz));

    // ---- phase 1: stage A'h0+A'h1; MFMA (0,1); hoist A-rows 64-127 reads ----
    if (pf) {
      stage_half256(A, lda, bm0,       kc, nA,         tid);
      stage_half256(A, lda, bm0 + 128, kc, nA + 16384, tid);
    }
    PH_BARRIER();
    MFMA_Q(0, 1);
#pragma unroll
    for (int m4 = 0; m4 < 4; ++m4)
#pragma unroll
      for (int ks = 0; ks < 2; ++ks)
        av[m4][ks] = *(const short8*)(Ab + ((64 + m4 * 16 + lo) * 128) + ((ks * 64 + hi * 16) ^ swz));

    // ---- phase 2: MFMA (1,0) ----
    PH_BARRIER();
    MFMA_Q(1, 0);

    // ---- phase 3: MFMA (1,1) ----
    PH_BARRIER();
    MFMA_Q(1, 1);
  }

  // epilogue: C/D layout row=(lane>>4)*4+reg, col = bn0 + wc*16 + ni*64 + lo
  if (MODE == 0) {
#pragma unroll
    for (int mi = 0; mi < 8; ++mi)
#pragma unroll
      for (int r = 0; r < 4; ++r) {
        int row = bm0 + wr * 128 + mi * 16 + hi * 4 + r;
#pragma unroll
        for (int ni = 0; ni < 4; ++ni) {
          int col = bn0 + wc * 16 + ni * 64 + lo;
          ((float*)Cp)[(size_t)row * ldc + col] = acc[mi][ni][r];
        }
      }
  } else if (bn0 < 8192) {
    // ---- q or k block: in-register RoPE (pairs ni0/ni1 and ni2/ni3 are d, d+64) ----
    short* qkvb = (short*)Cp;
    const int dd = wc * 16 + lo;   // d within head, 0..63
    const float inv = exp2f((float)dd * -0.2076205059304570f);
#pragma unroll
    for (int mi = 0; mi < 8; ++mi)
#pragma unroll
      for (int r = 0; r < 4; ++r) {
        int row = bm0 + wr * 128 + mi * 16 + hi * 4 + r;
        float pos = (float)positions[row];
        float s, c;
        sincosf(pos * inv, &s, &c);
        size_t base = (size_t)row * ldc + bn0 + wc * 16 + lo;
        float x1 = acc[mi][0][r], x2 = acc[mi][1][r];
        qkvb[base]       = f2bf(x1 * c - x2 * s);
        qkvb[base + 64]  = f2bf(x2 * c + x1 * s);
        float x3 = acc[mi][2][r], x4 = acc[mi][3][r];
        qkvb[base + 128] = f2bf(x3 * c - x4 * s);
        qkvb[base + 192] = f2bf(x4 * c + x3 * s);
      }
  } else {
    // ---- v block: emit V^T only (qkv's V region is never read) ----
    const int b = bm0 >> 11;
    const int s0 = (bm0 & 2047) + wr * 128;
#pragma unroll
    for (int mi = 0; mi < 8; ++mi)
#pragma unroll
      for (int ni = 0; ni < 4; ++ni) {
        int col = bn0 - 8192 + wc * 16 + ni * 64 + lo;
        int h = col >> 7, d = col & 127;
        short4v o;
#pragma unroll
        for (int r = 0; r < 4; ++r) o[r] = f2bf(acc[mi][ni][r]);
        *(short4v*)(Vtg + (size_t)((b * 32 + h) * 128 + d) * Sdim + s0 + mi * 16 + hi * 4) = o;
      }
  }
}

// ---------------- causal flash attention + piggybacked w_o^T transpose ----------------
__device__ __forceinline__ void stage_kv(const short* Kb, const short* Vtb, int kv0,
                                         char* kbuf, char* vbuf, int tid, int wave) {
#pragma unroll
  for (int i = 0; i < 4; ++i) {
    int p = i * 256 + tid;            // 16B chunk id in [0,1024)
    int r = p >> 4;                   // kv row (16 chunks/row)
    int c = (p & 15) ^ (r & 7);       // swizzled chunk within row
    gload_lds16(Kb + (size_t)(kv0 + r) * QKVLD + (c << 3),
                kbuf + ((i * 256 + wave * 64) << 4));
  }
#pragma unroll
  for (int i = 0; i < 4; ++i) {
    int p = i * 256 + tid;
    int r = p >> 3;                   // d row (8 chunks/row)
    int c = (p & 7) ^ (r & 7);        // swizzled chunk within row
    gload_lds16(Vtb + (size_t)r * Sdim + kv0 + (c << 3),
                vbuf + ((i * 256 + wave * 64) << 4));
  }
}

__global__ __launch_bounds__(256, 2) void k_attn(short* __restrict__ qkv,
                                                 const short* __restrict__ Vt,
                                                 const float* __restrict__ w_o,
                                                 short* __restrict__ Wot) {
  __shared__ __align__(16) char smem[81920];
  const int tid  = threadIdx.x;

  if (blockIdx.x >= 1024) {
    // ---- piggybacked w_o^T (64x64 tile; R=C=4096) ----
    float (*t)[65] = (float(*)[65])smem;
    const int idx = blockIdx.x - 1024;
    const int c0 = (idx & 63) << 6, r0 = (idx >> 6) << 6;
    const int ir = tid >> 4, ic = (tid & 15) << 2;
#pragma unroll
    for (int p = 0; p < 4; ++p) {
      const float4v v = *(const float4v*)(w_o + (size_t)(r0 + p * 16 + ir) * 4096 + c0 + ic);
      t[p * 16 + ir][ic] = v.x; t[p * 16 + ir][ic + 1] = v.y;
      t[p * 16 + ir][ic + 2] = v.z; t[p * 16 + ir][ic + 3] = v.w;
    }
    __syncthreads();
    const int oc = tid >> 3, orr = (tid & 7) << 3;
#pragma unroll
    for (int p = 0; p < 2; ++p) {
      int c = p * 32 + oc;
      short8 o;
#pragma unroll
      for (int j = 0; j < 8; ++j) o[j] = f2bf(t[orr + j][c]);
      *(short8*)(Wot + (size_t)(c0 + c) * 4096 + r0 + orr) = o;
    }
    return;
  }

  const int lane = tid & 63;
  const int wave = tid >> 6;
  const int lo = lane & 15, hi = lane >> 4;

  const int bid = blockIdx.x;
  const int lid = (bid & 7) * 128 + (bid >> 3);
  const int bh = lid >> 4;
  const int qt = 15 - (lid & 15);     // heavy tiles first
  const int b = bh >> 5, h = bh & 31;
  const int q0 = qt << 7;

  short* base = qkv + (size_t)b * Sdim * QKVLD;
  const short* Qb = base + h * Dh;
  const short* Kb = base + Hdim + h * Dh;
  const short* Vtb = Vt + (size_t)(b * 32 + h) * 128 * Sdim;
  const int qrow0 = q0 + wave * 32;

  short* Pw = (short*)(smem + 65536 + wave * 4096);

  const float SEXP = 0.088388347648318447f * 1.4426950408889634f;  // scale*log2e

  // Q into registers (A-frag layout), SEXP folded in-register.
  short8 qf[2][4];
#pragma unroll
  for (int mi = 0; mi < 2; ++mi)
#pragma unroll
    for (int ks = 0; ks < 4; ++ks) {
      qf[mi][ks] = *(const short8*)(Qb + (size_t)(qrow0 + mi * 16 + lo) * QKVLD + ks * 32 + hi * 8);
#pragma unroll
      for (int j = 0; j < 8; ++j)
        qf[mi][ks][j] = f2bf(bf2f(qf[mi][ks][j]) * SEXP);
    }

  f32x4 acc_o[2][9];
  float m_run[2][4];
#pragma unroll
  for (int mi = 0; mi < 2; ++mi) {
#pragma unroll
    for (int nf = 0; nf < 9; ++nf) acc_o[mi][nf] = (f32x4){0.f, 0.f, 0.f, 0.f};
#pragma unroll
    for (int r = 0; r < 4; ++r) m_run[mi][r] = -1e30f;
  }

  short8 vones;
#pragma unroll
  for (int j = 0; j < 8; ++j) vones[j] = (short)0x3F80;  // bf16 1.0

  const int nkv = (q0 + 128) >> 6;
  const int swz = (lo & 7) << 4;

  stage_kv(Kb, Vtb, 0, smem, smem + 16384, tid, wave);
  __syncthreads();

  int cur = 0;
  for (int kvt = 0; kvt < nkv; ++kvt) {
    const int kv0 = kvt << 6;
    if (kvt + 1 < nkv)
      stage_kv(Kb, Vtb, kv0 + 64, smem + (cur ^ 1) * 32768,
               smem + (cur ^ 1) * 32768 + 16384, tid, wave);

    if (kv0 <= qrow0 + 31) {
      const char* kl = smem + cur * 32768;
      const char* vl = smem + cur * 32768 + 16384;

      f32x4 accs[2][4];
#pragma unroll
      for (int mi = 0; mi < 2; ++mi)
#pragma unroll
        for (int nf = 0; nf < 4; ++nf) accs[mi][nf] = (f32x4){0.f, 0.f, 0.f, 0.f};
#pragma unroll
      for (int ks = 0; ks < 4; ++ks) {
        short8 kf[4];
#pragma unroll
        for (int nf = 0; nf < 4; ++nf) {
          int r = nf * 16 + lo;
          kf[nf] = *(const short8*)(kl + r * 256 + ((ks * 64 + hi * 16) ^ swz));
        }
        __builtin_amdgcn_s_setprio(1);
#pragma unroll
        for (int mi = 0; mi < 2; ++mi)
#pragma unroll
          for (int nf = 0; nf < 4; ++nf)
            accs[mi][nf] = __builtin_amdgcn_mfma_f32_16x16x32_bf16(qf[mi][ks], kf[nf], accs[mi][nf], 0, 0, 0);
        __builtin_amdgcn_s_setprio(0);
      }

      const bool needmask = (kv0 + 63 > qrow0);
      float pmax[2][4];
      bool okall = true;
#pragma unroll
      for (int mi = 0; mi < 2; ++mi) {
#pragma unroll
        for (int r = 0; r < 4; ++r) {
          const int qrow = qrow0 + mi * 16 + hi * 4 + r;
          if (needmask) {
#pragma unroll
            for (int nf = 0; nf < 4; ++nf) {
              int col = kv0 + nf * 16 + lo;
              accs[mi][nf][r] = (col <= qrow) ? accs[mi][nf][r] : -1e30f;
            }
          }
          float tmax = fmaxf(fmaxf(accs[mi][0][r], accs[mi][1][r]),
                             fmaxf(accs[mi][2][r], accs[mi][3][r]));
#pragma unroll
          for (int off = 1; off < 16; off <<= 1)
            tmax = fmaxf(tmax, __shfl_xor(tmax, off, 64));
          pmax[mi][r] = tmax;
          okall = okall && (tmax <= m_run[mi][r] + 8.0f);
        }
      }
      if (!__all(okall)) {
#pragma unroll
        for (int mi = 0; mi < 2; ++mi)
#pragma unroll
          for (int r = 0; r < 4; ++r) {
            float mnew = fmaxf(m_run[mi][r], pmax[mi][r]);
            float alpha = exp2f(m_run[mi][r] - mnew);
            m_run[mi][r] = mnew;
#pragma unroll
            for (int nf = 0; nf < 9; ++nf) acc_o[mi][nf][r] *= alpha;
          }
      }
#pragma unroll
      for (int mi = 0; mi < 2; ++mi)
#pragma unroll
        for (int r = 0; r < 4; ++r) {
          const int prow = mi * 16 + hi * 4 + r;
          const int psw = prow & 7;
#pragma unroll
          for (int nf = 0; nf < 4; ++nf) {
            float p = exp2f(accs[mi][nf][r] - m_run[mi][r]);
            int col = nf * 16 + lo;
            Pw[(prow << 6) + (((col >> 3) ^ psw) << 3) + (col & 7)] = f2bf(p);
          }
        }

#pragma unroll
      for (int ks = 0; ks < 2; ++ks) {
        short8 pf[2];
#pragma unroll
        for (int mi = 0; mi < 2; ++mi) {
          int prow = mi * 16 + lo;
          pf[mi] = *(const short8*)((const char*)Pw + prow * 128 + (((ks * 4 + hi) ^ (prow & 7)) << 4));
        }
        __builtin_amdgcn_s_setprio(1);
#pragma unroll
        for (int nf = 0; nf < 9; ++nf) {
          short8 vf;
          if (nf < 8) {
            int row = nf * 16 + lo;
            vf = *(const short8*)(vl + row * 128 + ((ks * 64 + hi * 16) ^ swz));
          } else {
            vf = vones;
          }
#pragma unroll
          for (int mi = 0; mi < 2; ++mi)
            acc_o[mi][nf] = __builtin_amdgcn_mfma_f32_16x16x32_bf16(pf[mi], vf, acc_o[mi][nf], 0, 0, 0);
        }
        __builtin_amdgcn_s_setprio(0);
      }
    }

    __syncthreads();
    cur ^= 1;
  }

  short* Osm = (short*)smem;   // [128][128]
#pragma unroll
  for (int mi = 0; mi < 2; ++mi)
#pragma unroll
    for (int r = 0; r < 4; ++r) {
      float inv = 1.0f / acc_o[mi][8][r];
      int row = wave * 32 + mi * 16 + hi * 4 + r;
#pragma unroll
      for (int nf = 0; nf < 8; ++nf)
        Osm[row * 128 + nf * 16 + lo] = f2bf(acc_o[mi][nf][r] * inv);
    }
  __syncthreads();
  short* Ob = base + h * Dh;
#pragma unroll
  for (int it = 0; it < 8; ++it) {
    int chunk = it * 256 + tid;
    int row = chunk >> 4, c8 = chunk & 15;
    *(short8*)(Ob + (size_t)(q0 + row) * QKVLD + c8 * 8) =
        *(const short8*)(Osm + row * 128 + c8 * 8);
  }
}

extern "C" void kernel_launch(void* const* d_in, const int* in_sizes, int n_in,
                              void* d_out, int out_size, void* d_ws, size_t ws_size,
                              hipStream_t stream) {
  const int*   positions = (const int*)d_in[0];
  const float* hidden    = (const float*)d_in[1];
  const float* w_pack    = (const float*)d_in[2];
  const float* w_o       = (const float*)d_in[3];
  float* out = (float*)d_out;

  char* ws = (char*)d_ws;
  short* Wpt  = (short*)ws;                                 // w_pack^T bf16 [12288][4096]
  short* qkvb = (short*)(ws + (size_t)12288 * 4096 * 2);    // qkv bf16 [4096][12288]
  short* Wot  = (short*)ws;                                 // w_o^T bf16 (reuses Wpt region)
  short* Hbf  = (short*)d_out;                              // hidden bf16 (d_out front 32MB)
  short* Vtg  = (short*)((char*)d_out + ((size_t)32 << 20)); // V^T bf16 (d_out back 32MB)

  // 1. hidden fp32 -> bf16 (dead after GEMM1)
  k_cvt<<<8192, 256, 0, stream>>>(hidden, Hbf, 4096 * 4096 / 8);
  // 2. w_pack^T bf16 (vectorized 64x64 transpose)
  k_tcvt64<<<dim3(12288 / 64, 4096 / 64), 256, 0, stream>>>(w_pack, Wpt, 4096, 12288);
  // 3. qkv = hidden @ w_pack, fused in-register RoPE (q/k) + V^T emit (v)
  k_gemm256<1><<<dim3(768), 512, 0, stream>>>(Hbf, 4096, Wpt, 4096, qkvb, QKVLD, 12288, 4096,
                                              positions, Vtg);
  // 4. attention (blocks 0..1023) + piggybacked w_o^T (blocks 1024..5119)
  k_attn<<<dim3(5120), 256, 0, stream>>>(qkvb, Vtg, w_o, Wot);
  // 5. out = O @ w_o (fp32)
  k_gemm256<0><<<dim3(256), 512, 0, stream>>>(qkvb, QKVLD, Wot, 4096, out, 4096, 4096, 4096,
                                              nullptr, nullptr);
}

// Round 16
// 716.816 us; speedup vs baseline: 1.0772x; 1.0168x over previous
//
#include <hip/hip_runtime.h>

// Problem constants
#define Sdim   2048
#define Hdim   4096
#define NHEADS 32
#define Dh     128
#define Mrows  4096      // B*S
#define QKVLD  12288     // 3*H

typedef __attribute__((ext_vector_type(8))) short short8;
typedef __attribute__((ext_vector_type(4))) short short4v;
typedef __attribute__((ext_vector_type(4))) float f32x4;
typedef __attribute__((ext_vector_type(4))) float float4v;

__device__ __forceinline__ short f2bf(float f) {
  union { float f; unsigned u; } x; x.f = f;
  unsigned r = x.u + 0x7fffu + ((x.u >> 16) & 1u);  // RNE
  return (short)(r >> 16);
}
__device__ __forceinline__ float bf2f(short s) {
  union { unsigned u; float f; } x; x.u = ((unsigned)(unsigned short)s) << 16;
  return x.f;
}

__device__ __forceinline__ void gload_lds16(const void* g, void* l) {
  __builtin_amdgcn_global_load_lds(
      (const __attribute__((address_space(1))) void*)g,
      (__attribute__((address_space(3))) void*)l, 16, 0, 0);
}

// ---- fused prep: blocks 0..8191 = hidden fp32->bf16; 8192..20479 = w_pack^T ----
__global__ void k_prep(const float* __restrict__ hidden, short* __restrict__ Hbf,
                       const float* __restrict__ w_pack, short* __restrict__ Wpt) {
  __shared__ float t[64][65];
  const int tid = threadIdx.x;
  if (blockIdx.x < 8192) {
    int idx = blockIdx.x * 256 + tid;          // 8 elems/thread over 4096*4096
    const float4v* s = (const float4v*)hidden + (size_t)idx * 2;
    float4v a = s[0], b = s[1];
    short8 o;
    o[0] = f2bf(a.x); o[1] = f2bf(a.y); o[2] = f2bf(a.z); o[3] = f2bf(a.w);
    o[4] = f2bf(b.x); o[5] = f2bf(b.y); o[6] = f2bf(b.z); o[7] = f2bf(b.w);
    *((short8*)Hbf + idx) = o;
  } else {
    // w_pack^T 64x64 tile: R=4096, C=12288; tiles (bx, by) = (idx%192, idx/192)
    const int idx = blockIdx.x - 8192;
    const int c0 = (idx % 192) * 64, r0 = (idx / 192) * 64;
    const int ir = tid >> 4, ic = (tid & 15) << 2;
#pragma unroll
    for (int p = 0; p < 4; ++p) {
      const float4v v = *(const float4v*)(w_pack + (size_t)(r0 + p * 16 + ir) * 12288 + c0 + ic);
      t[p * 16 + ir][ic] = v.x; t[p * 16 + ir][ic + 1] = v.y;
      t[p * 16 + ir][ic + 2] = v.z; t[p * 16 + ir][ic + 3] = v.w;
    }
    __syncthreads();
    const int oc = tid >> 3, orr = (tid & 7) << 3;
#pragma unroll
    for (int p = 0; p < 2; ++p) {
      int c = p * 32 + oc;
      short8 o;
#pragma unroll
      for (int j = 0; j < 8; ++j) o[j] = f2bf(t[orr + j][c]);
      *(short8*)(Wpt + (size_t)(c0 + c) * 4096 + r0 + orr) = o;
    }
  }
}

// ============ 256x256-tile bf16 GEMM, 8 waves, 4 phases/K-tile, counted vmcnt ============
// B-fragment column remap col = bn0 + wc*16 + ni*64 + lo. MODE 1 epilogue ropes q/k in
// fp32 (R16: 3 sincos + rotation recurrence — positions are affine within a wave-span)
// and emits V^T directly.
__device__ __forceinline__ void stage_half256(const short* G, int ld, int row0, int kcol,
                                              char* lds, int tid) {
#pragma unroll
  for (int j = 0; j < 2; ++j) {
    int p = j * 512 + tid;            // 16B chunk id in [0,1024): 8 chunks per 64-col row
    int r = p >> 3;
    int c = ((p & 7) ^ (r & 7)) << 3; // swizzled source column (elements)
    gload_lds16(G + (size_t)(row0 + r) * ld + kcol + c,
                lds + ((j * 512 + (tid & 448)) << 4));
  }
}

#define MFMA_Q(qm, qn)                                                                   \
  do {                                                                                   \
    __builtin_amdgcn_s_setprio(1);                                                       \
    _Pragma("unroll")                                                                    \
    for (int m4 = 0; m4 < 4; ++m4)                                                       \
      _Pragma("unroll")                                                                  \
      for (int n2 = 0; n2 < 2; ++n2) {                                                   \
        acc[(qm)*4+m4][(qn)*2+n2] = __builtin_amdgcn_mfma_f32_16x16x32_bf16(             \
            av[m4][0], bv[(qn)*2+n2][0], acc[(qm)*4+m4][(qn)*2+n2], 0, 0, 0);            \
        acc[(qm)*4+m4][(qn)*2+n2] = __builtin_amdgcn_mfma_f32_16x16x32_bf16(             \
            av[m4][1], bv[(qn)*2+n2][1], acc[(qm)*4+m4][(qn)*2+n2], 0, 0, 0);            \
      }                                                                                  \
    __builtin_amdgcn_s_setprio(0);                                                       \
  } while (0)

#define PH_BARRIER()                    \
  do {                                  \
    __builtin_amdgcn_s_barrier();       \
    __builtin_amdgcn_sched_barrier(0);  \
  } while (0)

template<int MODE>  // 0: fp32 direct store; 1: fused qkv epilogue (rope q/k, V^T emit)
__global__ __launch_bounds__(512, 2) void k_gemm256(const short* __restrict__ A, int lda,
                                                    const short* __restrict__ Bt, int ldb,
                                                    void* __restrict__ Cp, int ldc,
                                                    int Ndim, int Kdim,
                                                    const int* __restrict__ positions,
                                                    short* __restrict__ Vtg) {
  __shared__ __align__(16) char smem[131072];
  const int tid  = threadIdx.x;
  const int lane = tid & 63;
  const int wave = tid >> 6;
  const int lo = lane & 15, hi = lane >> 4;
  const int wr = wave >> 2, wc = wave & 3;   // 2M x 4N waves; per-wave out 128x64

  // T1: XCD-aware bijective block swizzle (grid % 8 == 0 for all our calls)
  const int nblk = gridDim.x;
  const int lid = (blockIdx.x & 7) * (nblk >> 3) + (blockIdx.x >> 3);
  const int nbn = Ndim >> 8;
  const int bm0 = (lid / nbn) << 8;
  const int bn0 = (lid % nbn) << 8;

  f32x4 acc[8][4];
#pragma unroll
  for (int i = 0; i < 8; ++i)
#pragma unroll
    for (int j = 0; j < 4; ++j) acc[i][j] = (f32x4){0.f, 0.f, 0.f, 0.f};

  short8 av[4][2], bv[4][2];
  const int swz = (lo & 7) << 4;

  // prologue: K-tile 0 -> slot 0
  stage_half256(Bt, ldb, bn0,       0, smem + 32768,         tid);
  stage_half256(Bt, ldb, bn0 + 128, 0, smem + 32768 + 16384, tid);
  stage_half256(A,  lda, bm0,       0, smem,                 tid);
  stage_half256(A,  lda, bm0 + 128, 0, smem + 16384,         tid);

  const int NK = Kdim >> 6;
  for (int kt = 0; kt < NK; ++kt) {
    const int cur = kt & 1;
    const char* Ab = smem + cur * 65536 + wr * 16384;   // wave's A half (128 rows)
    const char* Bb = smem + cur * 65536 + 32768;        // full B tile (256 rows)
    char* nA = smem + (cur ^ 1) * 65536;
    char* nB = nA + 32768;
    const int kc = (kt + 1) << 6;
    const bool pf = (kt + 1 < NK);

    // ---- phase 0: stage B'h0+B'h1; counted drain; read A[0-3],B[0-1]; MFMA (0,0) ----
    if (pf) {
      stage_half256(Bt, ldb, bn0,       kc, nB,         tid);
      stage_half256(Bt, ldb, bn0 + 128, kc, nB + 16384, tid);
      asm volatile("s_waitcnt vmcnt(4)" ::: "memory");   // prev 8 landed; own 4 in flight
    } else {
      asm volatile("s_waitcnt vmcnt(0)" ::: "memory");   // final tile: full drain
    }
    PH_BARRIER();   // after this, slot cur is fully landed for ALL waves
#pragma unroll
    for (int m4 = 0; m4 < 4; ++m4)
#pragma unroll
      for (int ks = 0; ks < 2; ++ks)
        av[m4][ks] = *(const short8*)(Ab + (m4 * 16 + lo) * 128 + ((ks * 64 + hi * 16) ^ swz));
#pragma unroll
    for (int ni = 0; ni < 2; ++ni)
#pragma unroll
      for (int ks = 0; ks < 2; ++ks)
        bv[ni][ks] = *(const short8*)(Bb + (wc * 16 + ni * 64 + lo) * 128 + ((ks * 64 + hi * 16) ^ swz));
    MFMA_Q(0, 0);
    // hoisted reads for phase 1 (slot cur is landed)
#pragma unroll
    for (int ni = 2; ni < 4; ++ni)
#pragma unroll
      for (int ks = 0; ks < 2; ++ks)
        bv[ni][ks] = *(const short8*)(Bb + (wc * 16 + ni * 64 + lo) * 128 + ((ks * 64 + hi * 16) ^ swz));

    // ---- phase 1: stage A'h0+A'h1; MFMA (0,1); hoist A-rows 64-127 reads ----
    if (pf) {
      stage_half256(A, lda, bm0,       kc, nA,         tid);
      stage_half256(A, lda, bm0 + 128, kc, nA + 16384, tid);
    }
    PH_BARRIER();
    MFMA_Q(0, 1);
#pragma unroll
    for (int m4 = 0; m4 < 4; ++m4)
#pragma unroll
      for (int ks = 0; ks < 2; ++ks)
        av[m4][ks] = *(const short8*)(Ab + ((64 + m4 * 16 + lo) * 128) + ((ks * 64 + hi * 16) ^ swz));

    // ---- phase 2: MFMA (1,0) ----
    PH_BARRIER();
    MFMA_Q(1, 0);

    // ---- phase 3: MFMA (1,1) ----
    PH_BARRIER();
    MFMA_Q(1, 1);
  }

  // epilogue: C/D layout row=(lane>>4)*4+reg, col = bn0 + wc*16 + ni*64 + lo
  if (MODE == 0) {
#pragma unroll
    for (int mi = 0; mi < 8; ++mi)
#pragma unroll
      for (int r = 0; r < 4; ++r) {
        int row = bm0 + wr * 128 + mi * 16 + hi * 4 + r;
#pragma unroll
        for (int ni = 0; ni < 4; ++ni) {
          int col = bn0 + wc * 16 + ni * 64 + lo;
          ((float*)Cp)[(size_t)row * ldc + col] = acc[mi][ni][r];
        }
      }
  } else if (bn0 < 8192) {
    // ---- q or k block: in-register RoPE via rotation recurrence ----
    // positions are affine (row % 2048) within the 128-row wave-span (no 2048-crossing:
    // bm0 is 256-aligned). 3 sincos + 31 complex rotations replace 32 sincos.
    short* qkvb = (short*)Cp;
    const int dd = wc * 16 + lo;   // d within head, 0..63
    const float inv = exp2f((float)dd * -0.2076205059304570f);
    const int row00 = bm0 + wr * 128 + hi * 4;
    float cm, sm, c1, s1, c16, s16;
    sincosf((float)positions[row00] * inv, &sm, &cm);
    sincosf(inv, &s1, &c1);
    sincosf(16.0f * inv, &s16, &c16);
#pragma unroll
    for (int mi = 0; mi < 8; ++mi) {
      float c = cm, s = sm;
#pragma unroll
      for (int r = 0; r < 4; ++r) {
        int row = row00 + mi * 16 + r;
        size_t base = (size_t)row * ldc + bn0 + wc * 16 + lo;
        float x1 = acc[mi][0][r], x2 = acc[mi][1][r];
        qkvb[base]       = f2bf(x1 * c - x2 * s);
        qkvb[base + 64]  = f2bf(x2 * c + x1 * s);
        float x3 = acc[mi][2][r], x4 = acc[mi][3][r];
        qkvb[base + 128] = f2bf(x3 * c - x4 * s);
        qkvb[base + 192] = f2bf(x4 * c + x3 * s);
        float cn = c * c1 - s * s1, sn = s * c1 + c * s1;   // rotate by inv
        c = cn; s = sn;
      }
      float cn = cm * c16 - sm * s16, sn = sm * c16 + cm * s16;  // rotate base by 16*inv
      cm = cn; sm = sn;
    }
  } else {
    // ---- v block: emit V^T only (qkv's V region is never read) ----
    const int b = bm0 >> 11;
    const int s0 = (bm0 & 2047) + wr * 128;
#pragma unroll
    for (int mi = 0; mi < 8; ++mi)
#pragma unroll
      for (int ni = 0; ni < 4; ++ni) {
        int col = bn0 - 8192 + wc * 16 + ni * 64 + lo;
        int h = col >> 7, d = col & 127;
        short4v o;
#pragma unroll
        for (int r = 0; r < 4; ++r) o[r] = f2bf(acc[mi][ni][r]);
        *(short4v*)(Vtg + (size_t)((b * 32 + h) * 128 + d) * Sdim + s0 + mi * 16 + hi * 4) = o;
      }
  }
}

// ---------------- causal flash attention + piggybacked w_o^T transpose ----------------
__device__ __forceinline__ void stage_kv(const short* Kb, const short* Vtb, int kv0,
                                         char* kbuf, char* vbuf, int tid, int wave) {
#pragma unroll
  for (int i = 0; i < 4; ++i) {
    int p = i * 256 + tid;            // 16B chunk id in [0,1024)
    int r = p >> 4;                   // kv row (16 chunks/row)
    int c = (p & 15) ^ (r & 7);       // swizzled chunk within row
    gload_lds16(Kb + (size_t)(kv0 + r) * QKVLD + (c << 3),
                kbuf + ((i * 256 + wave * 64) << 4));
  }
#pragma unroll
  for (int i = 0; i < 4; ++i) {
    int p = i * 256 + tid;
    int r = p >> 3;                   // d row (8 chunks/row)
    int c = (p & 7) ^ (r & 7);        // swizzled chunk within row
    gload_lds16(Vtb + (size_t)r * Sdim + kv0 + (c << 3),
                vbuf + ((i * 256 + wave * 64) << 4));
  }
}

__global__ __launch_bounds__(256, 2) void k_attn(short* __restrict__ qkv,
                                                 const short* __restrict__ Vt,
                                                 const float* __restrict__ w_o,
                                                 short* __restrict__ Wot) {
  __shared__ __align__(16) char smem[81920];
  const int tid  = threadIdx.x;

  if (blockIdx.x >= 1024) {
    // ---- piggybacked w_o^T (64x64 tile; R=C=4096) ----
    float (*t)[65] = (float(*)[65])smem;
    const int idx = blockIdx.x - 1024;
    const int c0 = (idx & 63) << 6, r0 = (idx >> 6) << 6;
    const int ir = tid >> 4, ic = (tid & 15) << 2;
#pragma unroll
    for (int p = 0; p < 4; ++p) {
      const float4v v = *(const float4v*)(w_o + (size_t)(r0 + p * 16 + ir) * 4096 + c0 + ic);
      t[p * 16 + ir][ic] = v.x; t[p * 16 + ir][ic + 1] = v.y;
      t[p * 16 + ir][ic + 2] = v.z; t[p * 16 + ir][ic + 3] = v.w;
    }
    __syncthreads();
    const int oc = tid >> 3, orr = (tid & 7) << 3;
#pragma unroll
    for (int p = 0; p < 2; ++p) {
      int c = p * 32 + oc;
      short8 o;
#pragma unroll
      for (int j = 0; j < 8; ++j) o[j] = f2bf(t[orr + j][c]);
      *(short8*)(Wot + (size_t)(c0 + c) * 4096 + r0 + orr) = o;
    }
    return;
  }

  const int lane = tid & 63;
  const int wave = tid >> 6;
  const int lo = lane & 15, hi = lane >> 4;

  const int bid = blockIdx.x;
  const int lid = (bid & 7) * 128 + (bid >> 3);
  const int bh = lid >> 4;
  const int qt = 15 - (lid & 15);     // heavy tiles first
  const int b = bh >> 5, h = bh & 31;
  const int q0 = qt << 7;

  short* base = qkv + (size_t)b * Sdim * QKVLD;
  const short* Qb = base + h * Dh;
  const short* Kb = base + Hdim + h * Dh;
  const short* Vtb = Vt + (size_t)(b * 32 + h) * 128 * Sdim;
  const int qrow0 = q0 + wave * 32;

  short* Pw = (short*)(smem + 65536 + wave * 4096);

  const float SEXP = 0.088388347648318447f * 1.4426950408889634f;  // scale*log2e

  // Q into registers (A-frag layout), SEXP folded in-register.
  short8 qf[2][4];
#pragma unroll
  for (int mi = 0; mi < 2; ++mi)
#pragma unroll
    for (int ks = 0; ks < 4; ++ks) {
      qf[mi][ks] = *(const short8*)(Qb + (size_t)(qrow0 + mi * 16 + lo) * QKVLD + ks * 32 + hi * 8);
#pragma unroll
      for (int j = 0; j < 8; ++j)
        qf[mi][ks][j] = f2bf(bf2f(qf[mi][ks][j]) * SEXP);
    }

  f32x4 acc_o[2][9];
  float m_run[2][4];
#pragma unroll
  for (int mi = 0; mi < 2; ++mi) {
#pragma unroll
    for (int nf = 0; nf < 9; ++nf) acc_o[mi][nf] = (f32x4){0.f, 0.f, 0.f, 0.f};
#pragma unroll
    for (int r = 0; r < 4; ++r) m_run[mi][r] = -1e30f;
  }

  short8 vones;
#pragma unroll
  for (int j = 0; j < 8; ++j) vones[j] = (short)0x3F80;  // bf16 1.0

  const int nkv = (q0 + 128) >> 6;
  const int swz = (lo & 7) << 4;

  stage_kv(Kb, Vtb, 0, smem, smem + 16384, tid, wave);
  __syncthreads();

  int cur = 0;
  for (int kvt = 0; kvt < nkv; ++kvt) {
    const int kv0 = kvt << 6;
    if (kvt + 1 < nkv)
      stage_kv(Kb, Vtb, kv0 + 64, smem + (cur ^ 1) * 32768,
               smem + (cur ^ 1) * 32768 + 16384, tid, wave);

    if (kv0 <= qrow0 + 31) {
      const char* kl = smem + cur * 32768;
      const char* vl = smem + cur * 32768 + 16384;

      f32x4 accs[2][4];
#pragma unroll
      for (int mi = 0; mi < 2; ++mi)
#pragma unroll
        for (int nf = 0; nf < 4; ++nf) accs[mi][nf] = (f32x4){0.f, 0.f, 0.f, 0.f};
#pragma unroll
      for (int ks = 0; ks < 4; ++ks) {
        short8 kf[4];
#pragma unroll
        for (int nf = 0; nf < 4; ++nf) {
          int r = nf * 16 + lo;
          kf[nf] = *(const short8*)(kl + r * 256 + ((ks * 64 + hi * 16) ^ swz));
        }
        __builtin_amdgcn_s_setprio(1);
#pragma unroll
        for (int mi = 0; mi < 2; ++mi)
#pragma unroll
          for (int nf = 0; nf < 4; ++nf)
            accs[mi][nf] = __builtin_amdgcn_mfma_f32_16x16x32_bf16(qf[mi][ks], kf[nf], accs[mi][nf], 0, 0, 0);
        __builtin_amdgcn_s_setprio(0);
      }

      const bool needmask = (kv0 + 63 > qrow0);
      float pmax[2][4];
      bool okall = true;
#pragma unroll
      for (int mi = 0; mi < 2; ++mi) {
#pragma unroll
        for (int r = 0; r < 4; ++r) {
          const int qrow = qrow0 + mi * 16 + hi * 4 + r;
          if (needmask) {
#pragma unroll
            for (int nf = 0; nf < 4; ++nf) {
              int col = kv0 + nf * 16 + lo;
              accs[mi][nf][r] = (col <= qrow) ? accs[mi][nf][r] : -1e30f;
            }
          }
          float tmax = fmaxf(fmaxf(accs[mi][0][r], accs[mi][1][r]),
                             fmaxf(accs[mi][2][r], accs[mi][3][r]));
#pragma unroll
          for (int off = 1; off < 16; off <<= 1)
            tmax = fmaxf(tmax, __shfl_xor(tmax, off, 64));
          pmax[mi][r] = tmax;
          okall = okall && (tmax <= m_run[mi][r] + 8.0f);
        }
      }
      if (!__all(okall)) {
#pragma unroll
        for (int mi = 0; mi < 2; ++mi)
#pragma unroll
          for (int r = 0; r < 4; ++r) {
            float mnew = fmaxf(m_run[mi][r], pmax[mi][r]);
            float alpha = exp2f(m_run[mi][r] - mnew);
            m_run[mi][r] = mnew;
#pragma unroll
            for (int nf = 0; nf < 9; ++nf) acc_o[mi][nf][r] *= alpha;
          }
      }
#pragma unroll
      for (int mi = 0; mi < 2; ++mi)
#pragma unroll
        for (int r = 0; r < 4; ++r) {
          const int prow = mi * 16 + hi * 4 + r;
          const int psw = prow & 7;
#pragma unroll
          for (int nf = 0; nf < 4; ++nf) {
            float p = exp2f(accs[mi][nf][r] - m_run[mi][r]);
            int col = nf * 16 + lo;
            Pw[(prow << 6) + (((col >> 3) ^ psw) << 3) + (col & 7)] = f2bf(p);
          }
        }

#pragma unroll
      for (int ks = 0; ks < 2; ++ks) {
        short8 pf[2];
#pragma unroll
        for (int mi = 0; mi < 2; ++mi) {
          int prow = mi * 16 + lo;
          pf[mi] = *(const short8*)((const char*)Pw + prow * 128 + (((ks * 4 + hi) ^ (prow & 7)) << 4));
        }
        __builtin_amdgcn_s_setprio(1);
#pragma unroll
        for (int nf = 0; nf < 9; ++nf) {
          short8 vf;
          if (nf < 8) {
            int row = nf * 16 + lo;
            vf = *(const short8*)(vl + row * 128 + ((ks * 64 + hi * 16) ^ swz));
          } else {
            vf = vones;
          }
#pragma unroll
          for (int mi = 0; mi < 2; ++mi)
            acc_o[mi][nf] = __builtin_amdgcn_mfma_f32_16x16x32_bf16(pf[mi], vf, acc_o[mi][nf], 0, 0, 0);
        }
        __builtin_amdgcn_s_setprio(0);
      }
    }

    __syncthreads();
    cur ^= 1;
  }

  short* Osm = (short*)smem;   // [128][128]
#pragma unroll
  for (int mi = 0; mi < 2; ++mi)
#pragma unroll
    for (int r = 0; r < 4; ++r) {
      float inv = 1.0f / acc_o[mi][8][r];
      int row = wave * 32 + mi * 16 + hi * 4 + r;
#pragma unroll
      for (int nf = 0; nf < 8; ++nf)
        Osm[row * 128 + nf * 16 + lo] = f2bf(acc_o[mi][nf][r] * inv);
    }
  __syncthreads();
  short* Ob = base + h * Dh;
#pragma unroll
  for (int it = 0; it < 8; ++it) {
    int chunk = it * 256 + tid;
    int row = chunk >> 4, c8 = chunk & 15;
    *(short8*)(Ob + (size_t)(q0 + row) * QKVLD + c8 * 8) =
        *(const short8*)(Osm + row * 128 + c8 * 8);
  }
}

extern "C" void kernel_launch(void* const* d_in, const int* in_sizes, int n_in,
                              void* d_out, int out_size, void* d_ws, size_t ws_size,
                              hipStream_t stream) {
  const int*   positions = (const int*)d_in[0];
  const float* hidden    = (const float*)d_in[1];
  const float* w_pack    = (const float*)d_in[2];
  const float* w_o       = (const float*)d_in[3];
  float* out = (float*)d_out;

  char* ws = (char*)d_ws;
  short* Wpt  = (short*)ws;                                 // w_pack^T bf16 [12288][4096]
  short* qkvb = (short*)(ws + (size_t)12288 * 4096 * 2);    // qkv bf16 [4096][12288]
  short* Wot  = (short*)ws;                                 // w_o^T bf16 (reuses Wpt region)
  short* Hbf  = (short*)d_out;                              // hidden bf16 (d_out front 32MB)
  short* Vtg  = (short*)((char*)d_out + ((size_t)32 << 20)); // V^T bf16 (d_out back 32MB)

  // 1. fused: hidden fp32->bf16 + w_pack^T (single dispatch)
  k_prep<<<20480, 256, 0, stream>>>(hidden, Hbf, w_pack, Wpt);
  // 2. qkv = hidden @ w_pack, fused in-register RoPE (q/k) + V^T emit (v)
  k_gemm256<1><<<dim3(768), 512, 0, stream>>>(Hbf, 4096, Wpt, 4096, qkvb, QKVLD, 12288, 4096,
                                              positions, Vtg);
  // 3. attention (blocks 0..1023) + piggybacked w_o^T (blocks 1024..5119)
  k_attn<<<dim3(5120), 256, 0, stream>>>(qkvb, Vtg, w_o, Wot);
  // 4. out = O @ w_o (fp32)
  k_gemm256<0><<<dim3(256), 512, 0, stream>>>(qkvb, QKVLD, Wot, 4096, out, 4096, 4096, 4096,
                                              nullptr, nullptr);
}